// Round 15
// baseline (325.119 us; speedup 1.0000x reference)
//
#include <hip/hip_runtime.h>
#include <hip/hip_bf16.h>

// SingleHeadCausalSelfAttention B=8 S=2048 H=1024 causal.
// R15 = R14 with stage slots moved for >=3-phase stage->wait lead (m201's
// margin): full-tile stages at P1(As1) P3(Bs0) P5(As0) P7(Bs1); waits vm(4)
// at P4/P8 only (uniform MT8/MT4; retire-set traced incl. prologue, drain,
// NT=2). Mechanism: ~12% of stage loads are HBM misses (~900cyc); R14's
// 2-phase-lead waits stalled all 8 barrier-locked waves at every P4/P8.

typedef __bf16 bf16x8 __attribute__((ext_vector_type(8)));
typedef float f32x4 __attribute__((ext_vector_type(4)));

static constexpr int HD = 1024;
static constexpr int BB = 8;
static constexpr int SS = 2048;
static constexpr long long SH = (long long)SS * HD;

__device__ __forceinline__ unsigned short f2bf(float f) {
  unsigned u = __builtin_bit_cast(unsigned, f);
  return (unsigned short)((u + 0x7FFFu + ((u >> 16) & 1u)) >> 16);
}
__device__ __forceinline__ f32x4 mfma16(bf16x8 a, bf16x8 b, f32x4 c) {
  return __builtin_amdgcn_mfma_f32_16x16x32_bf16(a, b, c, 0, 0, 0);
}
__device__ __forceinline__ void gload_lds16(const void* g, void* l) {
  __builtin_amdgcn_global_load_lds(
      (const __attribute__((address_space(1))) void*)g,
      (__attribute__((address_space(3))) void*)l, 16, 0, 0);
}

#define WAIT_LGKM0() do { asm volatile("s_waitcnt lgkmcnt(0)" ::: "memory"); \
  __builtin_amdgcn_sched_barrier(0); } while (0)
#define WAIT_VM(n) do { asm volatile("s_waitcnt vmcnt(" #n ")" ::: "memory"); \
} while (0)

// swizzled LDS read: logical (row, colbyte) -> byte ^ ((row&7)<<4)
__device__ __forceinline__ bf16x8 read_frag(const unsigned short* tile, int row,
                                            int colb) {
  int byte = row * 128 + colb;
  byte ^= (row & 7) << 4;
  return *reinterpret_cast<const bf16x8*>(
      reinterpret_cast<const char*>(tile) + byte);
}

// stage one half-tile (128 rows x 64 cols bf16); source cols pre-swizzled.
__device__ __forceinline__ void stage_half(const unsigned short* pM,
                                           long long ld, long long kt,
                                           unsigned short* tile, int h,
                                           int wid) {
  const unsigned short* s = pM + (long long)(h * 128) * ld + kt;
  gload_lds16(s, tile + h * 8192 + wid * 512);
  gload_lds16(s + 64 * ld, tile + h * 8192 + 4096 + wid * 512);
}
// stage a full A-tile (MT8: 2 halves = 4 loads; MT4: 1 half = 2 loads)
template <int MT>
__device__ __forceinline__ void stage_a(const unsigned short* pM, long long ld,
                                        long long kt, unsigned short* tile,
                                        int wid) {
  stage_half(pM, ld, kt, tile, 0, wid);
  if constexpr (MT == 8) stage_half(pM, ld, kt, tile, 1, wid);
}
// stage a full B-tile (2 halves = 4 loads)
__device__ __forceinline__ void stage_b(const unsigned short* pM, long long ld,
                                        long long kt, unsigned short* tile,
                                        int wid) {
  stage_half(pM, ld, kt, tile, 0, wid);
  stage_half(pM, ld, kt, tile, 1, wid);
}

template <int MT, int Q>
__device__ __forceinline__ void ds_a(const unsigned short* At, int rA, int cb,
                                     bf16x8 af[2][2]) {
  constexpr int FPP = MT / 4;
#pragma unroll
  for (int f = 0; f < FPP; ++f) {
    af[f][0] = read_frag(At, rA + (FPP * Q + f) * 16, cb);
    af[f][1] = read_frag(At, rA + (FPP * Q + f) * 16, 64 + cb);
  }
}
// HALF=0: ni 0,1 ; HALF=1: ni 2,3  (4 x ds_read_b128 each)
template <int HALF>
__device__ __forceinline__ void ds_b_half(const unsigned short* Bt, int rB,
                                          int cb, bf16x8 B[4][2]) {
#pragma unroll
  for (int ni = 2 * HALF; ni < 2 * HALF + 2; ++ni) {
    B[ni][0] = read_frag(Bt, rB + ni * 16, cb);
    B[ni][1] = read_frag(Bt, rB + ni * 16, 64 + cb);
  }
}
template <int MT, int Q>
__device__ __forceinline__ void mfma_q(const bf16x8 af[2][2],
                                       const bf16x8 B[4][2],
                                       f32x4 (&acc)[MT][4]) {
  constexpr int FPP = MT / 4;
#pragma unroll
  for (int f = 0; f < FPP; ++f)
#pragma unroll
    for (int ni = 0; ni < 4; ++ni) {
      acc[FPP * Q + f][ni] = mfma16(af[f][0], B[ni][0], acc[FPP * Q + f][ni]);
      acc[FPP * Q + f][ni] = mfma16(af[f][1], B[ni][1], acc[FPP * Q + f][ni]);
    }
}

#define PH_TAIL(QN, BRG) do { \
  __builtin_amdgcn_s_barrier(); \
  WAIT_LGKM0(); \
  __builtin_amdgcn_s_setprio(1); \
  mfma_q<MT, QN>(af, BRG, acc); \
  __builtin_amdgcn_s_setprio(0); \
  __builtin_amdgcn_s_barrier(); \
} while (0)

// MT*32-row x 256-col output tile over K = NT*64 (NT even, >=2).
// Stage slots: P1:As1<-A(2i+1) full, P3:Bs0<-B(2i+2) full, P5:As0<-A(2i+2)
// full, P7:Bs1<-B(2i+3) full. Waits vm(4) at P4/P8 only; every stage has
// >=3-phase lead to the wait that retires it (B-tiles: 5 phases).
template <int MT>
__device__ __forceinline__ void run_tile(
    const unsigned short* pA, const unsigned short* pB, long long lda,
    long long ldb, int NT, unsigned short* As0, unsigned short* As1,
    unsigned short* Bs0, unsigned short* Bs1, int wid, int rA, int rB, int cb,
    f32x4 (&acc)[MT][4]) {
  bf16x8 BA[4][2], BBr[4][2], af[2][2];
  stage_a<MT>(pA, lda, 0, As0, wid);
  stage_b(pB, ldb, 0, Bs0, wid);
  stage_b(pB, ldb, 64, Bs1, wid);
  WAIT_VM(4);  // retire As0+Bs0; leave Bs1's 4 (fixpoint)
  __builtin_amdgcn_s_barrier();
  ds_b_half<0>(Bs0, rB, cb, BA);  // BA-lo; BA-hi read at P1
  WAIT_LGKM0();
  __builtin_amdgcn_s_barrier();

  const int NITER = NT / 2 - 1;
  for (int i = 0; i < NITER; ++i) {
    const long long kA1 = (long long)(2 * i + 1) * 64;
    const long long kN2 = (long long)(2 * i + 2) * 64;
    const long long kB3 = (long long)(2 * i + 3) * 64;
    // P1: stage full As1 <- A(2i+1)
    ds_b_half<1>(Bs0, rB, cb, BA);
    ds_a<MT, 0>(As0, rA, cb, af); stage_a<MT>(pA, lda, kA1, As1, wid);
    PH_TAIL(0, BA);
    // P2
    ds_a<MT, 1>(As0, rA, cb, af); PH_TAIL(1, BA);
    // P3: stage full Bs0 <- B(2i+2)
    ds_a<MT, 2>(As0, rA, cb, af); stage_b(pB, ldb, kN2, Bs0, wid);
    PH_TAIL(2, BA);
    // P4: retire Bs1(P7-prev) + As1(P1); leave Bs0(P3)
    WAIT_VM(4);
    ds_a<MT, 3>(As0, rA, cb, af); ds_b_half<0>(Bs1, rB, cb, BBr);
    PH_TAIL(3, BA);
    // P5: stage full As0 <- A(2i+2)
    ds_b_half<1>(Bs1, rB, cb, BBr);
    ds_a<MT, 0>(As1, rA, cb, af); stage_a<MT>(pA, lda, kN2, As0, wid);
    PH_TAIL(0, BBr);
    // P6
    ds_a<MT, 1>(As1, rA, cb, af); PH_TAIL(1, BBr);
    // P7: stage full Bs1 <- B(2i+3)
    ds_a<MT, 2>(As1, rA, cb, af); stage_b(pB, ldb, kB3, Bs1, wid);
    PH_TAIL(2, BBr);
    // P8: retire Bs0(P3) + As0(P5); leave Bs1(P7)
    WAIT_VM(4);
    ds_a<MT, 3>(As1, rA, cb, af); ds_b_half<0>(Bs0, rB, cb, BA);
    PH_TAIL(3, BBr);
  }
  // drain: tile NT-2 (As0/Bs0, BA-lo already read) then NT-1 (As1 staged D1,
  // Bs1 staged last-P7 and still outstanding: 4 loads)
  const long long kL = (long long)(NT - 1) * 64;
  // D1: stage full As1 <- A(NT-1)
  ds_b_half<1>(Bs0, rB, cb, BA);
  ds_a<MT, 0>(As0, rA, cb, af); stage_a<MT>(pA, lda, kL, As1, wid);
  PH_TAIL(0, BA);
  // D2
  ds_a<MT, 1>(As0, rA, cb, af); PH_TAIL(1, BA);
  // D3
  ds_a<MT, 2>(As0, rA, cb, af); PH_TAIL(2, BA);
  // D4: retire Bs1 (B NT-1); leave As1's stages
  if constexpr (MT == 8) { WAIT_VM(4); } else { WAIT_VM(2); }
  ds_a<MT, 3>(As0, rA, cb, af); ds_b_half<0>(Bs1, rB, cb, BBr);
  PH_TAIL(3, BA);
  // D5: retire As1
  WAIT_VM(0);
  ds_b_half<1>(Bs1, rB, cb, BBr);
  ds_a<MT, 0>(As1, rA, cb, af); PH_TAIL(0, BBr);
  ds_a<MT, 1>(As1, rA, cb, af); PH_TAIL(1, BBr);
  ds_a<MT, 2>(As1, rA, cb, af); PH_TAIL(2, BBr);
  ds_a<MT, 3>(As1, rA, cb, af); PH_TAIL(3, BBr);
}

struct TC {
  int wid, lane, wm, wn, rA, rB, cb, rr, ccl, rowt, colg;
};
template <int MT>
__device__ __forceinline__ TC tc_setup() {
  TC t;
  const int tid = threadIdx.x;
  t.wid = tid >> 6;
  t.lane = tid & 63;
  t.wm = t.wid >> 2;
  t.wn = t.wid & 3;
  const int l16 = t.lane & 15;
  t.rA = t.wm * (MT * 16) + l16;
  t.rB = t.wn * 64 + l16;
  t.cb = (t.lane >> 4) * 16;
  t.rr = (t.lane >> 4) * 4;
  t.ccl = l16;
  t.rowt = tid >> 3;
  t.colg = (((tid & 7) ^ ((tid >> 3) & 7)) * 8);  // inverse of read swizzle
  return t;
}

#define SHARED_TILES8() \
  __shared__ __align__(16) unsigned short As0[16384], As1[16384]; \
  __shared__ __align__(16) unsigned short Bs0[16384], Bs1[16384]
#define SHARED_TILES4() \
  __shared__ __align__(16) unsigned short As0[8192], As1[8192]; \
  __shared__ __align__(16) unsigned short Bs0[16384], Bs1[16384]

// ---- QK fused projection: C[16384][2048] -> Q | K ----
__global__ __launch_bounds__(512, 2) void qk_kernel(
    const unsigned short* __restrict__ X, const unsigned short* __restrict__ W,
    const float* __restrict__ bq, const float* __restrict__ bk,
    unsigned short* __restrict__ Q, unsigned short* __restrict__ K) {
  SHARED_TILES8();
  const int lin = blockIdx.y * 8 + blockIdx.x;
  const int swz = (lin & 7) * 64 + (lin >> 3);
  const int m0 = (swz >> 3) * 256, n0 = (swz & 7) * 256;
  TC t = tc_setup<8>();
  const unsigned short* pA = X + (long long)(m0 + t.rowt) * HD + t.colg;
  const unsigned short* pB = W + (long long)(n0 + t.rowt) * HD + t.colg;
  f32x4 acc[8][4] = {};
  run_tile<8>(pA, pB, HD, HD, 16, As0, As1, Bs0, Bs1, t.wid, t.rA, t.rB, t.cb, acc);
#pragma unroll
  for (int mi = 0; mi < 8; ++mi)
#pragma unroll
    for (int ni = 0; ni < 4; ++ni) {
      const int gn = n0 + t.wn * 64 + ni * 16 + t.ccl;
      const float bias = (gn < 1024) ? bq[gn] : bk[gn - 1024];
      unsigned short* dst = (gn < 1024) ? (Q + gn) : (K + gn - 1024);
#pragma unroll
      for (int j = 0; j < 4; ++j) {
        const int gm = m0 + t.wm * 128 + mi * 16 + t.rr + j;
        dst[(long long)gm * HD] = f2bf(acc[mi][ni][j] + bias);
      }
    }
}

// ---- fused middle: blocks 0..255 = V^T GEMM; blocks 256..543 = scores ----
__global__ __launch_bounds__(512, 2) void mid_kernel(
    const unsigned short* __restrict__ Wv, const unsigned short* __restrict__ X,
    const float* __restrict__ bv, unsigned short* __restrict__ Vt,
    const unsigned short* __restrict__ Q, const unsigned short* __restrict__ Km,
    const int* __restrict__ mask, unsigned short* __restrict__ S,
    float* __restrict__ rowsum) {
  SHARED_TILES8();
  TC t = tc_setup<8>();
  if (blockIdx.x < 256) {
    const int lin = blockIdx.x;
    const int swz = (lin & 7) * 32 + (lin >> 3);
    const int m0 = (swz & 3) * 256, n0 = (swz >> 2) * 256;
    const unsigned short* pA = Wv + (long long)(m0 + t.rowt) * HD + t.colg;
    const unsigned short* pB = X + (long long)(n0 + t.rowt) * HD + t.colg;
    f32x4 acc[8][4] = {};
    run_tile<8>(pA, pB, HD, HD, 16, As0, As1, Bs0, Bs1, t.wid, t.rA, t.rB,
                t.cb, acc);
#pragma unroll
    for (int mi = 0; mi < 8; ++mi)
#pragma unroll
      for (int ni = 0; ni < 4; ++ni) {
        const int gn = n0 + t.wn * 64 + ni * 16 + t.ccl;  // gs
        const long long base = (long long)(gn >> 11) * SH + (gn & 2047);
#pragma unroll
        for (int j = 0; j < 4; ++j) {
          const int gm = m0 + t.wm * 128 + mi * 16 + t.rr + j;  // d
          Vt[base + (long long)gm * SS] = f2bf(acc[mi][ni][j] + bv[gm]);
        }
      }
  } else {
    const int s = blockIdx.x - 256;    // 0..287
    const long long b = s & 7;         // batch -> XCD pin
    int tt = s >> 3;                   // 0..35 triangle index
    int ii = 0, base = 0;
    while (tt >= base + ii + 1) { base += ii + 1; ++ii; }
    const int jj = tt - base;
    const int m0 = ii * 256, n0 = jj * 256;
    const unsigned short* pA =
        Q + b * SH + (long long)(m0 + t.rowt) * HD + t.colg;
    const unsigned short* pB =
        Km + b * SH + (long long)(n0 + t.rowt) * HD + t.colg;
    f32x4 acc[8][4] = {};
    run_tile<8>(pA, pB, HD, HD, 16, As0, As1, Bs0, Bs1, t.wid, t.rA, t.rB,
                t.cb, acc);
    unsigned short* Sb = S + b * (long long)SS * SS;
    const int* mb = mask + b * SS;
    float* rs = rowsum + b * SS;
    float* rsl = reinterpret_cast<float*>(As0);  // 4KB scratch, LDS dead
#pragma unroll
    for (int mi = 0; mi < 8; ++mi)
#pragma unroll
      for (int j = 0; j < 4; ++j) {
        const int gm = m0 + t.wm * 128 + mi * 16 + t.rr + j;
        float rsum = 0.0f;
#pragma unroll
        for (int ni = 0; ni < 4; ++ni) {
          const int gn = n0 + t.wn * 64 + ni * 16 + t.ccl;
          const bool dead = (gn > gm) || (mb[gn] == 0);
          const float pv = dead ? 0.0f : __expf(acc[mi][ni][j] * 0.03125f);
          Sb[(long long)gm * SS + gn] = f2bf(pv);
          rsum += pv;
        }
#pragma unroll
        for (int o = 1; o < 16; o <<= 1) rsum += __shfl_xor(rsum, o);
        if (t.ccl == 0)
          rsl[t.wn * 256 + (t.wm * 128 + mi * 16 + t.rr + j)] = rsum;
      }
    __syncthreads();
    const int tid = threadIdx.x;
    if (tid < 256) {
      const float v =
          rsl[tid] + rsl[256 + tid] + rsl[512 + tid] + rsl[768 + tid];
      atomicAdd(&rs[m0 + tid], v);
    }
  }
}

// ---- PV: paired m-tiles p/(15-p) (128 rows), uniform 34 K-tiles; /rowsum ----
__global__ __launch_bounds__(512, 2) void pv_kernel(
    const unsigned short* __restrict__ S, const unsigned short* __restrict__ Vt,
    const float* __restrict__ rowsum, unsigned short* __restrict__ AO) {
  SHARED_TILES4();
  const int bid = blockIdx.x;
  const long long b = bid & 7;       // batch -> XCD pin
  const int r = bid >> 3;            // 0..31
  const int p = r & 7;
  const int n0 = (r >> 3) * 256;
  const unsigned short* Sb = S + b * (long long)SS * SS;
  const unsigned short* Vb = Vt + b * SH;
  const float* rs = rowsum + b * SS;
  TC t = tc_setup<4>();

  for (int pass = 0; pass < 2; ++pass) {
    const int mi0 = pass ? 15 - p : p;
    const int m0 = mi0 * 128;
    const int NT = 2 * (mi0 + 1);
    const unsigned short* pA = Sb + (long long)(m0 + t.rowt) * SS + t.colg;
    const unsigned short* pB = Vb + (long long)(n0 + t.rowt) * SS + t.colg;
    f32x4 acc[4][4] = {};
    run_tile<4>(pA, pB, SS, SS, NT, As0, As1, Bs0, Bs1, t.wid, t.rA, t.rB,
                t.cb, acc);
#pragma unroll
    for (int mi = 0; mi < 4; ++mi)
#pragma unroll
      for (int j = 0; j < 4; ++j) {
        const int gm = m0 + t.wm * 64 + mi * 16 + t.rr + j;
        const float inv = 1.0f / rs[gm];
#pragma unroll
        for (int ni = 0; ni < 4; ++ni) {
          const int gn = n0 + t.wn * 64 + ni * 16 + t.ccl;
          AO[(b * SS + gm) * (long long)HD + gn] = f2bf(acc[mi][ni][j] * inv);
        }
      }
  }
}

// ---- output projection: f32 out ----
__global__ __launch_bounds__(512, 2) void oproj_kernel(
    const unsigned short* __restrict__ AO, const unsigned short* __restrict__ W,
    const float* __restrict__ bo, float* __restrict__ out) {
  SHARED_TILES8();
  const int lin = blockIdx.x;
  const int swz = (lin & 7) * 32 + (lin >> 3);
  const int n0 = (swz & 3) * 256, m0 = (swz >> 2) * 256;
  TC t = tc_setup<8>();
  const unsigned short* pA = AO + (long long)(m0 + t.rowt) * HD + t.colg;
  const unsigned short* pB = W + (long long)(n0 + t.rowt) * HD + t.colg;
  f32x4 acc[8][4] = {};
  run_tile<8>(pA, pB, HD, HD, 16, As0, As1, Bs0, Bs1, t.wid, t.rA, t.rB, t.cb, acc);
#pragma unroll
  for (int mi = 0; mi < 8; ++mi)
#pragma unroll
    for (int ni = 0; ni < 4; ++ni) {
      const int gn = n0 + t.wn * 64 + ni * 16 + t.ccl;
      const float bias = bo[gn];
#pragma unroll
      for (int j = 0; j < 4; ++j) {
        const int gm = m0 + t.wm * 128 + mi * 16 + t.rr + j;
        out[(long long)gm * HD + gn] = acc[mi][ni][j] + bias;
      }
    }
}

// ---- single cast dispatch: x + 4 weights -> bf16, rowsum -> 0 ----
__global__ __launch_bounds__(256) void cast_all(
    const float* __restrict__ x, const float* __restrict__ wq,
    const float* __restrict__ wk, const float* __restrict__ wv,
    const float* __restrict__ wo, unsigned short* __restrict__ xb,
    unsigned short* __restrict__ wqkb, unsigned short* __restrict__ wvb,
    unsigned short* __restrict__ wob, float* __restrict__ rowsum) {
  const int NX4 = (int)((long long)BB * SS * HD / 4);  // 4194304
  const int W4 = HD * HD / 4;                          // 262144
  const int RS4 = BB * SS / 4;                         // 4096
  const int TOT = NX4 + 4 * W4 + RS4;
  int idx = blockIdx.x * blockDim.x + threadIdx.x;
  const int stride = gridDim.x * blockDim.x;
  for (int u = idx; u < TOT; u += stride) {
    if (u >= NX4 + 4 * W4) {
      *reinterpret_cast<float4*>(rowsum + (u - NX4 - 4 * W4) * 4) =
          make_float4(0.f, 0.f, 0.f, 0.f);
      continue;
    }
    const float* src;
    unsigned short* dst;
    int off;
    if (u < NX4) {
      src = x; dst = xb; off = u;
    } else {
      const int v = u - NX4;
      const int seg = v >> 18;
      off = v & (W4 - 1);
      if (seg == 0) { src = wq; dst = wqkb; }
      else if (seg == 1) { src = wk; dst = wqkb + HD * HD; }
      else if (seg == 2) { src = wv; dst = wvb; }
      else { src = wo; dst = wob; }
    }
    float4 f = *reinterpret_cast<const float4*>(src + off * 4);
    ushort4 o;
    o.x = f2bf(f.x); o.y = f2bf(f.y); o.z = f2bf(f.z); o.w = f2bf(f.w);
    *reinterpret_cast<ushort4*>(dst + off * 4) = o;
  }
}

extern "C" void kernel_launch(void* const* d_in, const int* in_sizes, int n_in,
                              void* d_out, int out_size, void* d_ws, size_t ws_size,
                              hipStream_t stream) {
  const float* x = (const float*)d_in[0];
  const int* amask = (const int*)d_in[1];
  const float* wq = (const float*)d_in[2];
  const float* bq = (const float*)d_in[3];
  const float* wk = (const float*)d_in[4];
  const float* bk = (const float*)d_in[5];
  const float* wv = (const float*)d_in[6];
  const float* bv = (const float*)d_in[7];
  const float* wo = (const float*)d_in[8];
  const float* bo = (const float*)d_in[9];
  float* out = (float*)d_out;

  const long long NX = (long long)BB * SS * HD;
  char* p = (char*)d_ws;
  unsigned short* xb = (unsigned short*)p;    p += NX * 2;
  unsigned short* wqkb = (unsigned short*)p;  p += 2LL * HD * HD * 2;
  unsigned short* wvb = (unsigned short*)p;   p += (long long)HD * HD * 2;
  unsigned short* wob = (unsigned short*)p;   p += (long long)HD * HD * 2;
  unsigned short* Qb = (unsigned short*)p;    p += NX * 2;
  unsigned short* Kb = (unsigned short*)p;    p += NX * 2;
  unsigned short* Vtb = (unsigned short*)p;   p += NX * 2;  // [b][d][s]
  unsigned short* Sb = (unsigned short*)p;    p += (long long)BB * SS * SS * 2;
  float* rowsum = (float*)p;                  p += (long long)BB * SS * 4;
  unsigned short* AOb = xb;  // alias: x dead after QK + mid projections

  cast_all<<<dim3(2048), 256, 0, stream>>>(x, wq, wk, wv, wo, xb, wqkb, wvb,
                                           wob, rowsum);

  qk_kernel<<<dim3(8, 64), 512, 0, stream>>>(xb, wqkb, bq, bk, Qb, Kb);

  mid_kernel<<<dim3(544), 512, 0, stream>>>(wvb, xb, bv, Vtb, Qb, Kb, amask,
                                            Sb, rowsum);

  pv_kernel<<<dim3(256), 512, 0, stream>>>(Sb, Vtb, rowsum, AOb);

  oproj_kernel<<<dim3(256), 512, 0, stream>>>(AOb, wob, bo, out);
}

// Round 16
// 320.519 us; speedup vs baseline: 1.0144x; 1.0144x over previous
//
#include <hip/hip_runtime.h>
#include <hip/hip_bf16.h>

// SingleHeadCausalSelfAttention B=8 S=2048 H=1024 causal.
// R16 = R14 (best, 323.8us) minus the manual lgkmcnt(0)+sched_barrier(0)
// full-drain before each MFMA cluster. The ds_reads are plain C++ loads, so
// the compiler inserts staggered lgkmcnt waits INSIDE the MFMA cluster
// (m97 asm: lgkmcnt(4/3/1/0)) -- early MFMAs overlap late LDS service.
// Phase model: serial LDS(768cyc)+MFMA(155) -> overlapped max(...). Buffer
// safety: each wave's reads retire before its cluster ends; end barrier
// orders them before any overwrite (2+ phases later). vm waits unchanged.

typedef __bf16 bf16x8 __attribute__((ext_vector_type(8)));
typedef float f32x4 __attribute__((ext_vector_type(4)));

static constexpr int HD = 1024;
static constexpr int BB = 8;
static constexpr int SS = 2048;
static constexpr long long SH = (long long)SS * HD;

__device__ __forceinline__ unsigned short f2bf(float f) {
  unsigned u = __builtin_bit_cast(unsigned, f);
  return (unsigned short)((u + 0x7FFFu + ((u >> 16) & 1u)) >> 16);
}
__device__ __forceinline__ f32x4 mfma16(bf16x8 a, bf16x8 b, f32x4 c) {
  return __builtin_amdgcn_mfma_f32_16x16x32_bf16(a, b, c, 0, 0, 0);
}
__device__ __forceinline__ void gload_lds16(const void* g, void* l) {
  __builtin_amdgcn_global_load_lds(
      (const __attribute__((address_space(1))) void*)g,
      (__attribute__((address_space(3))) void*)l, 16, 0, 0);
}

#define WAIT_VM(n) do { asm volatile("s_waitcnt vmcnt(" #n ")" ::: "memory"); \
} while (0)

// swizzled LDS read: logical (row, colbyte) -> byte ^ ((row&7)<<4)
__device__ __forceinline__ bf16x8 read_frag(const unsigned short* tile, int row,
                                            int colb) {
  int byte = row * 128 + colb;
  byte ^= (row & 7) << 4;
  return *reinterpret_cast<const bf16x8*>(
      reinterpret_cast<const char*>(tile) + byte);
}

// stage one half-tile (128 rows x 64 cols bf16); source cols pre-swizzled.
__device__ __forceinline__ void stage_half(const unsigned short* pM,
                                           long long ld, long long kt,
                                           unsigned short* tile, int h,
                                           int wid) {
  const unsigned short* s = pM + (long long)(h * 128) * ld + kt;
  gload_lds16(s, tile + h * 8192 + wid * 512);
  gload_lds16(s + 64 * ld, tile + h * 8192 + 4096 + wid * 512);
}

template <int MT, int Q>
__device__ __forceinline__ void ds_a(const unsigned short* At, int rA, int cb,
                                     bf16x8 af[2][2]) {
  constexpr int FPP = MT / 4;
#pragma unroll
  for (int f = 0; f < FPP; ++f) {
    af[f][0] = read_frag(At, rA + (FPP * Q + f) * 16, cb);
    af[f][1] = read_frag(At, rA + (FPP * Q + f) * 16, 64 + cb);
  }
}
// HALF=0: ni 0,1 ; HALF=1: ni 2,3  (4 x ds_read_b128 each)
template <int HALF>
__device__ __forceinline__ void ds_b_half(const unsigned short* Bt, int rB,
                                          int cb, bf16x8 B[4][2]) {
#pragma unroll
  for (int ni = 2 * HALF; ni < 2 * HALF + 2; ++ni) {
    B[ni][0] = read_frag(Bt, rB + ni * 16, cb);
    B[ni][1] = read_frag(Bt, rB + ni * 16, 64 + cb);
  }
}
template <int MT, int Q>
__device__ __forceinline__ void mfma_q(const bf16x8 af[2][2],
                                       const bf16x8 B[4][2],
                                       f32x4 (&acc)[MT][4]) {
  constexpr int FPP = MT / 4;
#pragma unroll
  for (int f = 0; f < FPP; ++f)
#pragma unroll
    for (int ni = 0; ni < 4; ++ni) {
      acc[FPP * Q + f][ni] = mfma16(af[f][0], B[ni][0], acc[FPP * Q + f][ni]);
      acc[FPP * Q + f][ni] = mfma16(af[f][1], B[ni][1], acc[FPP * Q + f][ni]);
    }
}

// No manual lgkm drain: compiler inserts staggered lgkmcnt waits inside the
// MFMA cluster (plain-load dependencies), overlapping LDS service with MFMA.
#define PH_TAIL(QN, BRG) do { \
  __builtin_amdgcn_s_barrier(); \
  __builtin_amdgcn_s_setprio(1); \
  mfma_q<MT, QN>(af, BRG, acc); \
  __builtin_amdgcn_s_setprio(0); \
  __builtin_amdgcn_s_barrier(); \
} while (0)

// MT*32-row x 256-col output tile over K = NT*64 (NT even, >=2).
// Stage slots (iter i): P1:As1<-A(2i+1) [P2:h1 MT8], P3/P4:Bs0<-B(2i+2),
// P5:As0<-A(2i+2) [P6:h1 MT8], P7/P8:Bs1<-B(2i+3).
// Waits: vm(2) at P4-start and P8-start (retire-set traced, R14).
template <int MT>
__device__ __forceinline__ void run_tile(
    const unsigned short* pA, const unsigned short* pB, long long lda,
    long long ldb, int NT, unsigned short* As0, unsigned short* As1,
    unsigned short* Bs0, unsigned short* Bs1, int wid, int rA, int rB, int cb,
    f32x4 (&acc)[MT][4]) {
  bf16x8 BA[4][2], BBr[4][2], af[2][2];
  stage_half(pA, lda, 0, As0, 0, wid);
  if constexpr (MT == 8) stage_half(pA, lda, 0, As0, 1, wid);
  stage_half(pB, ldb, 0, Bs0, 0, wid);
  stage_half(pB, ldb, 0, Bs0, 1, wid);
  stage_half(pB, ldb, 64, Bs1, 0, wid);
  stage_half(pB, ldb, 64, Bs1, 1, wid);
  WAIT_VM(4);  // retire A0,B0; leave B1 (4 loads)
  __builtin_amdgcn_s_barrier();
  ds_b_half<0>(Bs0, rB, cb, BA);  // BA-lo; BA-hi read at P1
  __builtin_amdgcn_s_barrier();

  const int NITER = NT / 2 - 1;
  for (int i = 0; i < NITER; ++i) {
    const long long kA1 = (long long)(2 * i + 1) * 64;
    const long long kN2 = (long long)(2 * i + 2) * 64;
    const long long kB3 = (long long)(2 * i + 3) * 64;
    // P1
    ds_b_half<1>(Bs0, rB, cb, BA);
    ds_a<MT, 0>(As0, rA, cb, af); stage_half(pA, lda, kA1, As1, 0, wid);
    PH_TAIL(0, BA);
    // P2
    ds_a<MT, 1>(As0, rA, cb, af);
    if constexpr (MT == 8) stage_half(pA, lda, kA1, As1, 1, wid);
    PH_TAIL(1, BA);
    // P3
    ds_a<MT, 2>(As0, rA, cb, af); stage_half(pB, ldb, kN2, Bs0, 0, wid);
    PH_TAIL(2, BA);
    // P4
    WAIT_VM(2);  // retire prev Bs1 (B 2i+1) + As1 (P1/P2); leave P3
    ds_a<MT, 3>(As0, rA, cb, af); ds_b_half<0>(Bs1, rB, cb, BBr);
    stage_half(pB, ldb, kN2, Bs0, 1, wid);
    PH_TAIL(3, BA);
    // P5
    ds_b_half<1>(Bs1, rB, cb, BBr);
    ds_a<MT, 0>(As1, rA, cb, af); stage_half(pA, lda, kN2, As0, 0, wid);
    PH_TAIL(0, BBr);
    // P6
    ds_a<MT, 1>(As1, rA, cb, af);
    if constexpr (MT == 8) stage_half(pA, lda, kN2, As0, 1, wid);
    PH_TAIL(1, BBr);
    // P7
    ds_a<MT, 2>(As1, rA, cb, af); stage_half(pB, ldb, kB3, Bs1, 0, wid);
    PH_TAIL(2, BBr);
    // P8
    WAIT_VM(2);  // retire Bs0 (B 2i+2) + As0 (A 2i+2); leave P7
    ds_a<MT, 3>(As1, rA, cb, af); ds_b_half<0>(Bs0, rB, cb, BA);
    stage_half(pB, ldb, kB3, Bs1, 1, wid);
    PH_TAIL(3, BBr);
  }
  // drain: tile NT-2 (As0, BA) then NT-1 (As1 staged now, Bs1 in flight)
  const long long kL = (long long)(NT - 1) * 64;
  // D1
  ds_b_half<1>(Bs0, rB, cb, BA);
  ds_a<MT, 0>(As0, rA, cb, af); stage_half(pA, lda, kL, As1, 0, wid);
  PH_TAIL(0, BA);
  // D2
  ds_a<MT, 1>(As0, rA, cb, af);
  if constexpr (MT == 8) stage_half(pA, lda, kL, As1, 1, wid);
  PH_TAIL(1, BA);
  // D3
  ds_a<MT, 2>(As0, rA, cb, af); PH_TAIL(2, BA);
  // D4: retire Bs1 (B NT-1); leave As1 stages
  if constexpr (MT == 8) { WAIT_VM(4); } else { WAIT_VM(2); }
  ds_a<MT, 3>(As0, rA, cb, af); ds_b_half<0>(Bs1, rB, cb, BBr);
  PH_TAIL(3, BA);
  // D5: retire As1 stages
  WAIT_VM(0);
  ds_b_half<1>(Bs1, rB, cb, BBr);
  ds_a<MT, 0>(As1, rA, cb, af); PH_TAIL(0, BBr);
  ds_a<MT, 1>(As1, rA, cb, af); PH_TAIL(1, BBr);
  ds_a<MT, 2>(As1, rA, cb, af); PH_TAIL(2, BBr);
  ds_a<MT, 3>(As1, rA, cb, af); PH_TAIL(3, BBr);
}

struct TC {
  int wid, lane, wm, wn, rA, rB, cb, rr, ccl, rowt, colg;
};
template <int MT>
__device__ __forceinline__ TC tc_setup() {
  TC t;
  const int tid = threadIdx.x;
  t.wid = tid >> 6;
  t.lane = tid & 63;
  t.wm = t.wid >> 2;
  t.wn = t.wid & 3;
  const int l16 = t.lane & 15;
  t.rA = t.wm * (MT * 16) + l16;
  t.rB = t.wn * 64 + l16;
  t.cb = (t.lane >> 4) * 16;
  t.rr = (t.lane >> 4) * 4;
  t.ccl = l16;
  t.rowt = tid >> 3;
  t.colg = (((tid & 7) ^ ((tid >> 3) & 7)) * 8);  // inverse of read swizzle
  return t;
}

#define SHARED_TILES8() \
  __shared__ __align__(16) unsigned short As0[16384], As1[16384]; \
  __shared__ __align__(16) unsigned short Bs0[16384], Bs1[16384]
#define SHARED_TILES4() \
  __shared__ __align__(16) unsigned short As0[8192], As1[8192]; \
  __shared__ __align__(16) unsigned short Bs0[16384], Bs1[16384]

// ---- QK fused projection: C[16384][2048] -> Q | K ----
__global__ __launch_bounds__(512, 2) void qk_kernel(
    const unsigned short* __restrict__ X, const unsigned short* __restrict__ W,
    const float* __restrict__ bq, const float* __restrict__ bk,
    unsigned short* __restrict__ Q, unsigned short* __restrict__ K) {
  SHARED_TILES8();
  const int lin = blockIdx.y * 8 + blockIdx.x;
  const int swz = (lin & 7) * 64 + (lin >> 3);
  const int m0 = (swz >> 3) * 256, n0 = (swz & 7) * 256;
  TC t = tc_setup<8>();
  const unsigned short* pA = X + (long long)(m0 + t.rowt) * HD + t.colg;
  const unsigned short* pB = W + (long long)(n0 + t.rowt) * HD + t.colg;
  f32x4 acc[8][4] = {};
  run_tile<8>(pA, pB, HD, HD, 16, As0, As1, Bs0, Bs1, t.wid, t.rA, t.rB, t.cb, acc);
#pragma unroll
  for (int mi = 0; mi < 8; ++mi)
#pragma unroll
    for (int ni = 0; ni < 4; ++ni) {
      const int gn = n0 + t.wn * 64 + ni * 16 + t.ccl;
      const float bias = (gn < 1024) ? bq[gn] : bk[gn - 1024];
      unsigned short* dst = (gn < 1024) ? (Q + gn) : (K + gn - 1024);
#pragma unroll
      for (int j = 0; j < 4; ++j) {
        const int gm = m0 + t.wm * 128 + mi * 16 + t.rr + j;
        dst[(long long)gm * HD] = f2bf(acc[mi][ni][j] + bias);
      }
    }
}

// ---- fused middle: blocks 0..255 = V^T GEMM; blocks 256..543 = scores ----
__global__ __launch_bounds__(512, 2) void mid_kernel(
    const unsigned short* __restrict__ Wv, const unsigned short* __restrict__ X,
    const float* __restrict__ bv, unsigned short* __restrict__ Vt,
    const unsigned short* __restrict__ Q, const unsigned short* __restrict__ Km,
    const int* __restrict__ mask, unsigned short* __restrict__ S,
    float* __restrict__ rowsum) {
  SHARED_TILES8();
  TC t = tc_setup<8>();
  if (blockIdx.x < 256) {
    const int lin = blockIdx.x;
    const int swz = (lin & 7) * 32 + (lin >> 3);
    const int m0 = (swz & 3) * 256, n0 = (swz >> 2) * 256;
    const unsigned short* pA = Wv + (long long)(m0 + t.rowt) * HD + t.colg;
    const unsigned short* pB = X + (long long)(n0 + t.rowt) * HD + t.colg;
    f32x4 acc[8][4] = {};
    run_tile<8>(pA, pB, HD, HD, 16, As0, As1, Bs0, Bs1, t.wid, t.rA, t.rB,
                t.cb, acc);
#pragma unroll
    for (int mi = 0; mi < 8; ++mi)
#pragma unroll
      for (int ni = 0; ni < 4; ++ni) {
        const int gn = n0 + t.wn * 64 + ni * 16 + t.ccl;  // gs
        const long long base = (long long)(gn >> 11) * SH + (gn & 2047);
#pragma unroll
        for (int j = 0; j < 4; ++j) {
          const int gm = m0 + t.wm * 128 + mi * 16 + t.rr + j;  // d
          Vt[base + (long long)gm * SS] = f2bf(acc[mi][ni][j] + bv[gm]);
        }
      }
  } else {
    const int s = blockIdx.x - 256;    // 0..287
    const long long b = s & 7;         // batch -> XCD pin
    int tt = s >> 3;                   // 0..35 triangle index
    int ii = 0, base = 0;
    while (tt >= base + ii + 1) { base += ii + 1; ++ii; }
    const int jj = tt - base;
    const int m0 = ii * 256, n0 = jj * 256;
    const unsigned short* pA =
        Q + b * SH + (long long)(m0 + t.rowt) * HD + t.colg;
    const unsigned short* pB =
        Km + b * SH + (long long)(n0 + t.rowt) * HD + t.colg;
    f32x4 acc[8][4] = {};
    run_tile<8>(pA, pB, HD, HD, 16, As0, As1, Bs0, Bs1, t.wid, t.rA, t.rB,
                t.cb, acc);
    unsigned short* Sb = S + b * (long long)SS * SS;
    const int* mb = mask + b * SS;
    float* rs = rowsum + b * SS;
    float* rsl = reinterpret_cast<float*>(As0);  // 4KB scratch, LDS dead
#pragma unroll
    for (int mi = 0; mi < 8; ++mi)
#pragma unroll
      for (int j = 0; j < 4; ++j) {
        const int gm = m0 + t.wm * 128 + mi * 16 + t.rr + j;
        float rsum = 0.0f;
#pragma unroll
        for (int ni = 0; ni < 4; ++ni) {
          const int gn = n0 + t.wn * 64 + ni * 16 + t.ccl;
          const bool dead = (gn > gm) || (mb[gn] == 0);
          const float pv = dead ? 0.0f : __expf(acc[mi][ni][j] * 0.03125f);
          Sb[(long long)gm * SS + gn] = f2bf(pv);
          rsum += pv;
        }
#pragma unroll
        for (int o = 1; o < 16; o <<= 1) rsum += __shfl_xor(rsum, o);
        if (t.ccl == 0)
          rsl[t.wn * 256 + (t.wm * 128 + mi * 16 + t.rr + j)] = rsum;
      }
    __syncthreads();
    const int tid = threadIdx.x;
    if (tid < 256) {
      const float v =
          rsl[tid] + rsl[256 + tid] + rsl[512 + tid] + rsl[768 + tid];
      atomicAdd(&rs[m0 + tid], v);
    }
  }
}

// ---- PV: paired m-tiles p/(15-p) (128 rows), uniform 34 K-tiles; /rowsum ----
__global__ __launch_bounds__(512, 2) void pv_kernel(
    const unsigned short* __restrict__ S, const unsigned short* __restrict__ Vt,
    const float* __restrict__ rowsum, unsigned short* __restrict__ AO) {
  SHARED_TILES4();
  const int bid = blockIdx.x;
  const long long b = bid & 7;       // batch -> XCD pin
  const int r = bid >> 3;            // 0..31
  const int p = r & 7;
  const int n0 = (r >> 3) * 256;
  const unsigned short* Sb = S + b * (long long)SS * SS;
  const unsigned short* Vb = Vt + b * SH;
  const float* rs = rowsum + b * SS;
  TC t = tc_setup<4>();

  for (int pass = 0; pass < 2; ++pass) {
    const int mi0 = pass ? 15 - p : p;
    const int m0 = mi0 * 128;
    const int NT = 2 * (mi0 + 1);
    const unsigned short* pA = Sb + (long long)(m0 + t.rowt) * SS + t.colg;
    const unsigned short* pB = Vb + (long long)(n0 + t.rowt) * SS + t.colg;
    f32x4 acc[4][4] = {};
    run_tile<4>(pA, pB, SS, SS, NT, As0, As1, Bs0, Bs1, t.wid, t.rA, t.rB,
                t.cb, acc);
#pragma unroll
    for (int mi = 0; mi < 4; ++mi)
#pragma unroll
      for (int j = 0; j < 4; ++j) {
        const int gm = m0 + t.wm * 64 + mi * 16 + t.rr + j;
        const float inv = 1.0f / rs[gm];
#pragma unroll
        for (int ni = 0; ni < 4; ++ni) {
          const int gn = n0 + t.wn * 64 + ni * 16 + t.ccl;
          AO[(b * SS + gm) * (long long)HD + gn] = f2bf(acc[mi][ni][j] * inv);
        }
      }
  }
}

// ---- output projection: f32 out ----
__global__ __launch_bounds__(512, 2) void oproj_kernel(
    const unsigned short* __restrict__ AO, const unsigned short* __restrict__ W,
    const float* __restrict__ bo, float* __restrict__ out) {
  SHARED_TILES8();
  const int lin = blockIdx.x;
  const int swz = (lin & 7) * 32 + (lin >> 3);
  const int n0 = (swz & 3) * 256, m0 = (swz >> 2) * 256;
  TC t = tc_setup<8>();
  const unsigned short* pA = AO + (long long)(m0 + t.rowt) * HD + t.colg;
  const unsigned short* pB = W + (long long)(n0 + t.rowt) * HD + t.colg;
  f32x4 acc[8][4] = {};
  run_tile<8>(pA, pB, HD, HD, 16, As0, As1, Bs0, Bs1, t.wid, t.rA, t.rB, t.cb, acc);
#pragma unroll
  for (int mi = 0; mi < 8; ++mi)
#pragma unroll
    for (int ni = 0; ni < 4; ++ni) {
      const int gn = n0 + t.wn * 64 + ni * 16 + t.ccl;
      const float bias = bo[gn];
#pragma unroll
      for (int j = 0; j < 4; ++j) {
        const int gm = m0 + t.wm * 128 + mi * 16 + t.rr + j;
        out[(long long)gm * HD + gn] = acc[mi][ni][j] + bias;
      }
    }
}

// ---- single cast dispatch: x + 4 weights -> bf16, rowsum -> 0 ----
__global__ __launch_bounds__(256) void cast_all(
    const float* __restrict__ x, const float* __restrict__ wq,
    const float* __restrict__ wk, const float* __restrict__ wv,
    const float* __restrict__ wo, unsigned short* __restrict__ xb,
    unsigned short* __restrict__ wqkb, unsigned short* __restrict__ wvb,
    unsigned short* __restrict__ wob, float* __restrict__ rowsum) {
  const int NX4 = (int)((long long)BB * SS * HD / 4);  // 4194304
  const int W4 = HD * HD / 4;                          // 262144
  const int RS4 = BB * SS / 4;                         // 4096
  const int TOT = NX4 + 4 * W4 + RS4;
  int idx = blockIdx.x * blockDim.x + threadIdx.x;
  const int stride = gridDim.x * blockDim.x;
  for (int u = idx; u < TOT; u += stride) {
    if (u >= NX4 + 4 * W4) {
      *reinterpret_cast<float4*>(rowsum + (u - NX4 - 4 * W4) * 4) =
          make_float4(0.f, 0.f, 0.f, 0.f);
      continue;
    }
    const float* src;
    unsigned short* dst;
    int off;
    if (u < NX4) {
      src = x; dst = xb; off = u;
    } else {
      const int v = u - NX4;
      const int seg = v >> 18;
      off = v & (W4 - 1);
      if (seg == 0) { src = wq; dst = wqkb; }
      else if (seg == 1) { src = wk; dst = wqkb + HD * HD; }
      else if (seg == 2) { src = wv; dst = wvb; }
      else { src = wo; dst = wob; }
    }
    float4 f = *reinterpret_cast<const float4*>(src + off * 4);
    ushort4 o;
    o.x = f2bf(f.x); o.y = f2bf(f.y); o.z = f2bf(f.z); o.w = f2bf(f.w);
    *reinterpret_cast<ushort4*>(dst + off * 4) = o;
  }
}

extern "C" void kernel_launch(void* const* d_in, const int* in_sizes, int n_in,
                              void* d_out, int out_size, void* d_ws, size_t ws_size,
                              hipStream_t stream) {
  const float* x = (const float*)d_in[0];
  const int* amask = (const int*)d_in[1];
  const float* wq = (const float*)d_in[2];
  const float* bq = (const float*)d_in[3];
  const float* wk = (const float*)d_in[4];
  const float* bk = (const float*)d_in[5];
  const float* wv = (const float*)d_in[6];
  const float* bv = (const float*)d_in[7];
  const float* wo = (const float*)d_in[8];
  const float* bo = (const float*)d_in[9];
  float* out = (float*)d_out;

  const long long NX = (long long)BB * SS * HD;
  char* p = (char*)d_ws;
  unsigned short* xb = (unsigned short*)p;    p += NX * 2;
  unsigned short* wqkb = (unsigned short*)p;  p += 2LL * HD * HD * 2;
  unsigned short* wvb = (unsigned short*)p;   p += (long long)HD * HD * 2;
  unsigned short* wob = (unsigned short*)p;   p += (long long)HD * HD * 2;
  unsigned short* Qb = (unsigned short*)p;    p += NX * 2;
  unsigned short* Kb = (unsigned short*)p;    p += NX * 2;
  unsigned short* Vtb = (unsigned short*)p;   p += NX * 2;  // [b][d][s]
  unsigned short* Sb = (unsigned short*)p;    p += (long long)BB * SS * SS * 2;
  float* rowsum = (float*)p;                  p += (long long)BB * SS * 4;
  unsigned short* AOb = xb;  // alias: x dead after QK + mid projections

  cast_all<<<dim3(2048), 256, 0, stream>>>(x, wq, wk, wv, wo, xb, wqkb, wvb,
                                           wob, rowsum);

  qk_kernel<<<dim3(8, 64), 512, 0, stream>>>(xb, wqkb, bq, bk, Qb, Kb);

  mid_kernel<<<dim3(544), 512, 0, stream>>>(wvb, xb, bv, Vtb, Qb, Kb, amask,
                                            Sb, rowsum);

  pv_kernel<<<dim3(256), 512, 0, stream>>>(Sb, Vtb, rowsum, AOb);

  oproj_kernel<<<dim3(256), 512, 0, stream>>>(AOb, wob, bo, out);
}

// Round 17
// 317.071 us; speedup vs baseline: 1.0254x; 1.0109x over previous
//
#include <hip/hip_runtime.h>
#include <hip/hip_bf16.h>

// SingleHeadCausalSelfAttention B=8 S=2048 H=1024 causal.
// R17 = R16 (best, 320.5us) with ONE barrier per phase instead of two.
// Safety proof: reads of a region complete inside the reading phase's MFMA
// cluster (register deps force lgkm waits); the END-of-phase barrier then
// orders them before any later stage-issue, and gload LDS-writes cannot land
// before issue. Staged-data visibility: vm-waits precede the end barrier,
// which publishes before next phase's reads. Saves 8 sync points/iteration.

typedef __bf16 bf16x8 __attribute__((ext_vector_type(8)));
typedef float f32x4 __attribute__((ext_vector_type(4)));

static constexpr int HD = 1024;
static constexpr int BB = 8;
static constexpr int SS = 2048;
static constexpr long long SH = (long long)SS * HD;

__device__ __forceinline__ unsigned short f2bf(float f) {
  unsigned u = __builtin_bit_cast(unsigned, f);
  return (unsigned short)((u + 0x7FFFu + ((u >> 16) & 1u)) >> 16);
}
__device__ __forceinline__ f32x4 mfma16(bf16x8 a, bf16x8 b, f32x4 c) {
  return __builtin_amdgcn_mfma_f32_16x16x32_bf16(a, b, c, 0, 0, 0);
}
__device__ __forceinline__ void gload_lds16(const void* g, void* l) {
  __builtin_amdgcn_global_load_lds(
      (const __attribute__((address_space(1))) void*)g,
      (__attribute__((address_space(3))) void*)l, 16, 0, 0);
}

#define WAIT_VM(n) do { asm volatile("s_waitcnt vmcnt(" #n ")" ::: "memory"); \
} while (0)

// swizzled LDS read: logical (row, colbyte) -> byte ^ ((row&7)<<4)
__device__ __forceinline__ bf16x8 read_frag(const unsigned short* tile, int row,
                                            int colb) {
  int byte = row * 128 + colb;
  byte ^= (row & 7) << 4;
  return *reinterpret_cast<const bf16x8*>(
      reinterpret_cast<const char*>(tile) + byte);
}

// stage one half-tile (128 rows x 64 cols bf16); source cols pre-swizzled.
__device__ __forceinline__ void stage_half(const unsigned short* pM,
                                           long long ld, long long kt,
                                           unsigned short* tile, int h,
                                           int wid) {
  const unsigned short* s = pM + (long long)(h * 128) * ld + kt;
  gload_lds16(s, tile + h * 8192 + wid * 512);
  gload_lds16(s + 64 * ld, tile + h * 8192 + 4096 + wid * 512);
}

template <int MT, int Q>
__device__ __forceinline__ void ds_a(const unsigned short* At, int rA, int cb,
                                     bf16x8 af[2][2]) {
  constexpr int FPP = MT / 4;
#pragma unroll
  for (int f = 0; f < FPP; ++f) {
    af[f][0] = read_frag(At, rA + (FPP * Q + f) * 16, cb);
    af[f][1] = read_frag(At, rA + (FPP * Q + f) * 16, 64 + cb);
  }
}
// HALF=0: ni 0,1 ; HALF=1: ni 2,3  (4 x ds_read_b128 each)
template <int HALF>
__device__ __forceinline__ void ds_b_half(const unsigned short* Bt, int rB,
                                          int cb, bf16x8 B[4][2]) {
#pragma unroll
  for (int ni = 2 * HALF; ni < 2 * HALF + 2; ++ni) {
    B[ni][0] = read_frag(Bt, rB + ni * 16, cb);
    B[ni][1] = read_frag(Bt, rB + ni * 16, 64 + cb);
  }
}
template <int MT, int Q>
__device__ __forceinline__ void mfma_q(const bf16x8 af[2][2],
                                       const bf16x8 B[4][2],
                                       f32x4 (&acc)[MT][4]) {
  constexpr int FPP = MT / 4;
#pragma unroll
  for (int f = 0; f < FPP; ++f)
#pragma unroll
    for (int ni = 0; ni < 4; ++ni) {
      acc[FPP * Q + f][ni] = mfma16(af[f][0], B[ni][0], acc[FPP * Q + f][ni]);
      acc[FPP * Q + f][ni] = mfma16(af[f][1], B[ni][1], acc[FPP * Q + f][ni]);
    }
}

// Single barrier per phase (at END). Reads complete inside the MFMA cluster
// via compiler-staggered lgkm waits; end barrier orders them before any
// later stage-issue of the same region.
#define PH_TAIL(QN, BRG) do { \
  __builtin_amdgcn_s_setprio(1); \
  mfma_q<MT, QN>(af, BRG, acc); \
  __builtin_amdgcn_s_setprio(0); \
  __builtin_amdgcn_s_barrier(); \
} while (0)

// MT*32-row x 256-col output tile over K = NT*64 (NT even, >=2).
// Stage slots (iter i): P1:As1<-A(2i+1) [P2:h1 MT8], P3/P4:Bs0<-B(2i+2),
// P5:As0<-A(2i+2) [P6:h1 MT8], P7/P8:Bs1<-B(2i+3).
// Waits: vm(2) at P4-start and P8-start (retire-set traced, R14).
template <int MT>
__device__ __forceinline__ void run_tile(
    const unsigned short* pA, const unsigned short* pB, long long lda,
    long long ldb, int NT, unsigned short* As0, unsigned short* As1,
    unsigned short* Bs0, unsigned short* Bs1, int wid, int rA, int rB, int cb,
    f32x4 (&acc)[MT][4]) {
  bf16x8 BA[4][2], BBr[4][2], af[2][2];
  stage_half(pA, lda, 0, As0, 0, wid);
  if constexpr (MT == 8) stage_half(pA, lda, 0, As0, 1, wid);
  stage_half(pB, ldb, 0, Bs0, 0, wid);
  stage_half(pB, ldb, 0, Bs0, 1, wid);
  stage_half(pB, ldb, 64, Bs1, 0, wid);
  stage_half(pB, ldb, 64, Bs1, 1, wid);
  WAIT_VM(4);  // retire A0,B0; leave B1 (4 loads)
  __builtin_amdgcn_s_barrier();
  ds_b_half<0>(Bs0, rB, cb, BA);  // BA-lo; BA-hi read at P1

  const int NITER = NT / 2 - 1;
  for (int i = 0; i < NITER; ++i) {
    const long long kA1 = (long long)(2 * i + 1) * 64;
    const long long kN2 = (long long)(2 * i + 2) * 64;
    const long long kB3 = (long long)(2 * i + 3) * 64;
    // P1
    ds_b_half<1>(Bs0, rB, cb, BA);
    ds_a<MT, 0>(As0, rA, cb, af); stage_half(pA, lda, kA1, As1, 0, wid);
    PH_TAIL(0, BA);
    // P2
    ds_a<MT, 1>(As0, rA, cb, af);
    if constexpr (MT == 8) stage_half(pA, lda, kA1, As1, 1, wid);
    PH_TAIL(1, BA);
    // P3
    ds_a<MT, 2>(As0, rA, cb, af); stage_half(pB, ldb, kN2, Bs0, 0, wid);
    PH_TAIL(2, BA);
    // P4
    WAIT_VM(2);  // retire prev Bs1 (B 2i+1) + As1 (P1/P2); leave P3
    ds_a<MT, 3>(As0, rA, cb, af); ds_b_half<0>(Bs1, rB, cb, BBr);
    stage_half(pB, ldb, kN2, Bs0, 1, wid);
    PH_TAIL(3, BA);
    // P5
    ds_b_half<1>(Bs1, rB, cb, BBr);
    ds_a<MT, 0>(As1, rA, cb, af); stage_half(pA, lda, kN2, As0, 0, wid);
    PH_TAIL(0, BBr);
    // P6
    ds_a<MT, 1>(As1, rA, cb, af);
    if constexpr (MT == 8) stage_half(pA, lda, kN2, As0, 1, wid);
    PH_TAIL(1, BBr);
    // P7
    ds_a<MT, 2>(As1, rA, cb, af); stage_half(pB, ldb, kB3, Bs1, 0, wid);
    PH_TAIL(2, BBr);
    // P8
    WAIT_VM(2);  // retire Bs0 (B 2i+2) + As0 (A 2i+2); leave P7
    ds_a<MT, 3>(As1, rA, cb, af); ds_b_half<0>(Bs0, rB, cb, BA);
    stage_half(pB, ldb, kB3, Bs1, 1, wid);
    PH_TAIL(3, BBr);
  }
  // drain: tile NT-2 (As0, BA) then NT-1 (As1 staged now, Bs1 in flight)
  const long long kL = (long long)(NT - 1) * 64;
  // D1
  ds_b_half<1>(Bs0, rB, cb, BA);
  ds_a<MT, 0>(As0, rA, cb, af); stage_half(pA, lda, kL, As1, 0, wid);
  PH_TAIL(0, BA);
  // D2
  ds_a<MT, 1>(As0, rA, cb, af);
  if constexpr (MT == 8) stage_half(pA, lda, kL, As1, 1, wid);
  PH_TAIL(1, BA);
  // D3
  ds_a<MT, 2>(As0, rA, cb, af); PH_TAIL(2, BA);
  // D4: retire Bs1 (B NT-1); leave As1 stages
  if constexpr (MT == 8) { WAIT_VM(4); } else { WAIT_VM(2); }
  ds_a<MT, 3>(As0, rA, cb, af); ds_b_half<0>(Bs1, rB, cb, BBr);
  PH_TAIL(3, BA);
  // D5: retire As1 stages
  WAIT_VM(0);
  ds_b_half<1>(Bs1, rB, cb, BBr);
  ds_a<MT, 0>(As1, rA, cb, af); PH_TAIL(0, BBr);
  ds_a<MT, 1>(As1, rA, cb, af); PH_TAIL(1, BBr);
  ds_a<MT, 2>(As1, rA, cb, af); PH_TAIL(2, BBr);
  ds_a<MT, 3>(As1, rA, cb, af); PH_TAIL(3, BBr);
}

struct TC {
  int wid, lane, wm, wn, rA, rB, cb, rr, ccl, rowt, colg;
};
template <int MT>
__device__ __forceinline__ TC tc_setup() {
  TC t;
  const int tid = threadIdx.x;
  t.wid = tid >> 6;
  t.lane = tid & 63;
  t.wm = t.wid >> 2;
  t.wn = t.wid & 3;
  const int l16 = t.lane & 15;
  t.rA = t.wm * (MT * 16) + l16;
  t.rB = t.wn * 64 + l16;
  t.cb = (t.lane >> 4) * 16;
  t.rr = (t.lane >> 4) * 4;
  t.ccl = l16;
  t.rowt = tid >> 3;
  t.colg = (((tid & 7) ^ ((tid >> 3) & 7)) * 8);  // inverse of read swizzle
  return t;
}

#define SHARED_TILES8() \
  __shared__ __align__(16) unsigned short As0[16384], As1[16384]; \
  __shared__ __align__(16) unsigned short Bs0[16384], Bs1[16384]
#define SHARED_TILES4() \
  __shared__ __align__(16) unsigned short As0[8192], As1[8192]; \
  __shared__ __align__(16) unsigned short Bs0[16384], Bs1[16384]

// ---- QK fused projection: C[16384][2048] -> Q | K ----
__global__ __launch_bounds__(512, 2) void qk_kernel(
    const unsigned short* __restrict__ X, const unsigned short* __restrict__ W,
    const float* __restrict__ bq, const float* __restrict__ bk,
    unsigned short* __restrict__ Q, unsigned short* __restrict__ K) {
  SHARED_TILES8();
  const int lin = blockIdx.y * 8 + blockIdx.x;
  const int swz = (lin & 7) * 64 + (lin >> 3);
  const int m0 = (swz >> 3) * 256, n0 = (swz & 7) * 256;
  TC t = tc_setup<8>();
  const unsigned short* pA = X + (long long)(m0 + t.rowt) * HD + t.colg;
  const unsigned short* pB = W + (long long)(n0 + t.rowt) * HD + t.colg;
  f32x4 acc[8][4] = {};
  run_tile<8>(pA, pB, HD, HD, 16, As0, As1, Bs0, Bs1, t.wid, t.rA, t.rB, t.cb, acc);
#pragma unroll
  for (int mi = 0; mi < 8; ++mi)
#pragma unroll
    for (int ni = 0; ni < 4; ++ni) {
      const int gn = n0 + t.wn * 64 + ni * 16 + t.ccl;
      const float bias = (gn < 1024) ? bq[gn] : bk[gn - 1024];
      unsigned short* dst = (gn < 1024) ? (Q + gn) : (K + gn - 1024);
#pragma unroll
      for (int j = 0; j < 4; ++j) {
        const int gm = m0 + t.wm * 128 + mi * 16 + t.rr + j;
        dst[(long long)gm * HD] = f2bf(acc[mi][ni][j] + bias);
      }
    }
}

// ---- fused middle: blocks 0..255 = V^T GEMM; blocks 256..543 = scores ----
__global__ __launch_bounds__(512, 2) void mid_kernel(
    const unsigned short* __restrict__ Wv, const unsigned short* __restrict__ X,
    const float* __restrict__ bv, unsigned short* __restrict__ Vt,
    const unsigned short* __restrict__ Q, const unsigned short* __restrict__ Km,
    const int* __restrict__ mask, unsigned short* __restrict__ S,
    float* __restrict__ rowsum) {
  SHARED_TILES8();
  TC t = tc_setup<8>();
  if (blockIdx.x < 256) {
    const int lin = blockIdx.x;
    const int swz = (lin & 7) * 32 + (lin >> 3);
    const int m0 = (swz & 3) * 256, n0 = (swz >> 2) * 256;
    const unsigned short* pA = Wv + (long long)(m0 + t.rowt) * HD + t.colg;
    const unsigned short* pB = X + (long long)(n0 + t.rowt) * HD + t.colg;
    f32x4 acc[8][4] = {};
    run_tile<8>(pA, pB, HD, HD, 16, As0, As1, Bs0, Bs1, t.wid, t.rA, t.rB,
                t.cb, acc);
#pragma unroll
    for (int mi = 0; mi < 8; ++mi)
#pragma unroll
      for (int ni = 0; ni < 4; ++ni) {
        const int gn = n0 + t.wn * 64 + ni * 16 + t.ccl;  // gs
        const long long base = (long long)(gn >> 11) * SH + (gn & 2047);
#pragma unroll
        for (int j = 0; j < 4; ++j) {
          const int gm = m0 + t.wm * 128 + mi * 16 + t.rr + j;  // d
          Vt[base + (long long)gm * SS] = f2bf(acc[mi][ni][j] + bv[gm]);
        }
      }
  } else {
    const int s = blockIdx.x - 256;    // 0..287
    const long long b = s & 7;         // batch -> XCD pin
    int tt = s >> 3;                   // 0..35 triangle index
    int ii = 0, base = 0;
    while (tt >= base + ii + 1) { base += ii + 1; ++ii; }
    const int jj = tt - base;
    const int m0 = ii * 256, n0 = jj * 256;
    const unsigned short* pA =
        Q + b * SH + (long long)(m0 + t.rowt) * HD + t.colg;
    const unsigned short* pB =
        Km + b * SH + (long long)(n0 + t.rowt) * HD + t.colg;
    f32x4 acc[8][4] = {};
    run_tile<8>(pA, pB, HD, HD, 16, As0, As1, Bs0, Bs1, t.wid, t.rA, t.rB,
                t.cb, acc);
    unsigned short* Sb = S + b * (long long)SS * SS;
    const int* mb = mask + b * SS;
    float* rs = rowsum + b * SS;
    float* rsl = reinterpret_cast<float*>(As0);  // 4KB scratch, LDS dead
#pragma unroll
    for (int mi = 0; mi < 8; ++mi)
#pragma unroll
      for (int j = 0; j < 4; ++j) {
        const int gm = m0 + t.wm * 128 + mi * 16 + t.rr + j;
        float rsum = 0.0f;
#pragma unroll
        for (int ni = 0; ni < 4; ++ni) {
          const int gn = n0 + t.wn * 64 + ni * 16 + t.ccl;
          const bool dead = (gn > gm) || (mb[gn] == 0);
          const float pv = dead ? 0.0f : __expf(acc[mi][ni][j] * 0.03125f);
          Sb[(long long)gm * SS + gn] = f2bf(pv);
          rsum += pv;
        }
#pragma unroll
        for (int o = 1; o < 16; o <<= 1) rsum += __shfl_xor(rsum, o);
        if (t.ccl == 0)
          rsl[t.wn * 256 + (t.wm * 128 + mi * 16 + t.rr + j)] = rsum;
      }
    __syncthreads();
    const int tid = threadIdx.x;
    if (tid < 256) {
      const float v =
          rsl[tid] + rsl[256 + tid] + rsl[512 + tid] + rsl[768 + tid];
      atomicAdd(&rs[m0 + tid], v);
    }
  }
}

// ---- PV: paired m-tiles p/(15-p) (128 rows), uniform 34 K-tiles; /rowsum ----
__global__ __launch_bounds__(512, 2) void pv_kernel(
    const unsigned short* __restrict__ S, const unsigned short* __restrict__ Vt,
    const float* __restrict__ rowsum, unsigned short* __restrict__ AO) {
  SHARED_TILES4();
  const int bid = blockIdx.x;
  const long long b = bid & 7;       // batch -> XCD pin
  const int r = bid >> 3;            // 0..31
  const int p = r & 7;
  const int n0 = (r >> 3) * 256;
  const unsigned short* Sb = S + b * (long long)SS * SS;
  const unsigned short* Vb = Vt + b * SH;
  const float* rs = rowsum + b * SS;
  TC t = tc_setup<4>();

  for (int pass = 0; pass < 2; ++pass) {
    const int mi0 = pass ? 15 - p : p;
    const int m0 = mi0 * 128;
    const int NT = 2 * (mi0 + 1);
    const unsigned short* pA = Sb + (long long)(m0 + t.rowt) * SS + t.colg;
    const unsigned short* pB = Vb + (long long)(n0 + t.rowt) * SS + t.colg;
    f32x4 acc[4][4] = {};
    run_tile<4>(pA, pB, SS, SS, NT, As0, As1, Bs0, Bs1, t.wid, t.rA, t.rB,
                t.cb, acc);
#pragma unroll
    for (int mi = 0; mi < 4; ++mi)
#pragma unroll
      for (int j = 0; j < 4; ++j) {
        const int gm = m0 + t.wm * 64 + mi * 16 + t.rr + j;
        const float inv = 1.0f / rs[gm];
#pragma unroll
        for (int ni = 0; ni < 4; ++ni) {
          const int gn = n0 + t.wn * 64 + ni * 16 + t.ccl;
          AO[(b * SS + gm) * (long long)HD + gn] = f2bf(acc[mi][ni][j] * inv);
        }
      }
    __syncthreads();  // LDS reuse safety between passes
  }
}

// ---- output projection: f32 out ----
__global__ __launch_bounds__(512, 2) void oproj_kernel(
    const unsigned short* __restrict__ AO, const unsigned short* __restrict__ W,
    const float* __restrict__ bo, float* __restrict__ out) {
  SHARED_TILES8();
  const int lin = blockIdx.x;
  const int swz = (lin & 7) * 32 + (lin >> 3);
  const int n0 = (swz & 3) * 256, m0 = (swz >> 2) * 256;
  TC t = tc_setup<8>();
  const unsigned short* pA = AO + (long long)(m0 + t.rowt) * HD + t.colg;
  const unsigned short* pB = W + (long long)(n0 + t.rowt) * HD + t.colg;
  f32x4 acc[8][4] = {};
  run_tile<8>(pA, pB, HD, HD, 16, As0, As1, Bs0, Bs1, t.wid, t.rA, t.rB, t.cb, acc);
#pragma unroll
  for (int mi = 0; mi < 8; ++mi)
#pragma unroll
    for (int ni = 0; ni < 4; ++ni) {
      const int gn = n0 + t.wn * 64 + ni * 16 + t.ccl;
      const float bias = bo[gn];
#pragma unroll
      for (int j = 0; j < 4; ++j) {
        const int gm = m0 + t.wm * 128 + mi * 16 + t.rr + j;
        out[(long long)gm * HD + gn] = acc[mi][ni][j] + bias;
      }
    }
}

// ---- single cast dispatch: x + 4 weights -> bf16, rowsum -> 0 ----
__global__ __launch_bounds__(256) void cast_all(
    const float* __restrict__ x, const float* __restrict__ wq,
    const float* __restrict__ wk, const float* __restrict__ wv,
    const float* __restrict__ wo, unsigned short* __restrict__ xb,
    unsigned short* __restrict__ wqkb, unsigned short* __restrict__ wvb,
    unsigned short* __restrict__ wob, float* __restrict__ rowsum) {
  const int NX4 = (int)((long long)BB * SS * HD / 4);  // 4194304
  const int W4 = HD * HD / 4;                          // 262144
  const int RS4 = BB * SS / 4;                         // 4096
  const int TOT = NX4 + 4 * W4 + RS4;
  int idx = blockIdx.x * blockDim.x + threadIdx.x;
  const int stride = gridDim.x * blockDim.x;
  for (int u = idx; u < TOT; u += stride) {
    if (u >= NX4 + 4 * W4) {
      *reinterpret_cast<float4*>(rowsum + (u - NX4 - 4 * W4) * 4) =
          make_float4(0.f, 0.f, 0.f, 0.f);
      continue;
    }
    const float* src;
    unsigned short* dst;
    int off;
    if (u < NX4) {
      src = x; dst = xb; off = u;
    } else {
      const int v = u - NX4;
      const int seg = v >> 18;
      off = v & (W4 - 1);
      if (seg == 0) { src = wq; dst = wqkb; }
      else if (seg == 1) { src = wk; dst = wqkb + HD * HD; }
      else if (seg == 2) { src = wv; dst = wvb; }
      else { src = wo; dst = wob; }
    }
    float4 f = *reinterpret_cast<const float4*>(src + off * 4);
    ushort4 o;
    o.x = f2bf(f.x); o.y = f2bf(f.y); o.z = f2bf(f.z); o.w = f2bf(f.w);
    *reinterpret_cast<ushort4*>(dst + off * 4) = o;
  }
}

extern "C" void kernel_launch(void* const* d_in, const int* in_sizes, int n_in,
                              void* d_out, int out_size, void* d_ws, size_t ws_size,
                              hipStream_t stream) {
  const float* x = (const float*)d_in[0];
  const int* amask = (const int*)d_in[1];
  const float* wq = (const float*)d_in[2];
  const float* bq = (const float*)d_in[3];
  const float* wk = (const float*)d_in[4];
  const float* bk = (const float*)d_in[5];
  const float* wv = (const float*)d_in[6];
  const float* bv = (const float*)d_in[7];
  const float* wo = (const float*)d_in[8];
  const float* bo = (const float*)d_in[9];
  float* out = (float*)d_out;

  const long long NX = (long long)BB * SS * HD;
  char* p = (char*)d_ws;
  unsigned short* xb = (unsigned short*)p;    p += NX * 2;
  unsigned short* wqkb = (unsigned short*)p;  p += 2LL * HD * HD * 2;
  unsigned short* wvb = (unsigned short*)p;   p += (long long)HD * HD * 2;
  unsigned short* wob = (unsigned short*)p;   p += (long long)HD * HD * 2;
  unsigned short* Qb = (unsigned short*)p;    p += NX * 2;
  unsigned short* Kb = (unsigned short*)p;    p += NX * 2;
  unsigned short* Vtb = (unsigned short*)p;   p += NX * 2;  // [b][d][s]
  unsigned short* Sb = (unsigned short*)p;    p += (long long)BB * SS * SS * 2;
  float* rowsum = (float*)p;                  p += (long long)BB * SS * 4;
  unsigned short* AOb = xb;  // alias: x dead after QK + mid projections

  cast_all<<<dim3(2048), 256, 0, stream>>>(x, wq, wk, wv, wo, xb, wqkb, wvb,
                                           wob, rowsum);

  qk_kernel<<<dim3(8, 64), 512, 0, stream>>>(xb, wqkb, bq, bk, Qb, Kb);

  mid_kernel<<<dim3(544), 512, 0, stream>>>(wvb, xb, bv, Vtb, Qb, Kb, amask,
                                            Sb, rowsum);

  pv_kernel<<<dim3(256), 512, 0, stream>>>(Sb, Vtb, rowsum, AOb);

  oproj_kernel<<<dim3(256), 512, 0, stream>>>(AOb, wob, bo, out);
}

// Round 18
// 300.198 us; speedup vs baseline: 1.0830x; 1.0562x over previous
//
#include <hip/hip_runtime.h>
#include <hip/hip_bf16.h>

// SingleHeadCausalSelfAttention B=8 S=2048 H=1024 causal.
// R18 = R17 (best, 317.1us) + mid tail-round fix: 544 uniform tiles forced a
// 3rd nearly-idle round (ceil(544/256)); now 512 full tiles + the last 32
// scores tiles (row-block ii=7) split into 64 MT4 half-tiles dispatched last
// -> makespan 3u -> ~2.5u (~20us). All GEMM/phase structure unchanged.

typedef __bf16 bf16x8 __attribute__((ext_vector_type(8)));
typedef float f32x4 __attribute__((ext_vector_type(4)));

static constexpr int HD = 1024;
static constexpr int BB = 8;
static constexpr int SS = 2048;
static constexpr long long SH = (long long)SS * HD;

__device__ __forceinline__ unsigned short f2bf(float f) {
  unsigned u = __builtin_bit_cast(unsigned, f);
  return (unsigned short)((u + 0x7FFFu + ((u >> 16) & 1u)) >> 16);
}
__device__ __forceinline__ f32x4 mfma16(bf16x8 a, bf16x8 b, f32x4 c) {
  return __builtin_amdgcn_mfma_f32_16x16x32_bf16(a, b, c, 0, 0, 0);
}
__device__ __forceinline__ void gload_lds16(const void* g, void* l) {
  __builtin_amdgcn_global_load_lds(
      (const __attribute__((address_space(1))) void*)g,
      (__attribute__((address_space(3))) void*)l, 16, 0, 0);
}

#define WAIT_VM(n) do { asm volatile("s_waitcnt vmcnt(" #n ")" ::: "memory"); \
} while (0)

// swizzled LDS read: logical (row, colbyte) -> byte ^ ((row&7)<<4)
__device__ __forceinline__ bf16x8 read_frag(const unsigned short* tile, int row,
                                            int colb) {
  int byte = row * 128 + colb;
  byte ^= (row & 7) << 4;
  return *reinterpret_cast<const bf16x8*>(
      reinterpret_cast<const char*>(tile) + byte);
}

// stage one half-tile (128 rows x 64 cols bf16); source cols pre-swizzled.
__device__ __forceinline__ void stage_half(const unsigned short* pM,
                                           long long ld, long long kt,
                                           unsigned short* tile, int h,
                                           int wid) {
  const unsigned short* s = pM + (long long)(h * 128) * ld + kt;
  gload_lds16(s, tile + h * 8192 + wid * 512);
  gload_lds16(s + 64 * ld, tile + h * 8192 + 4096 + wid * 512);
}

template <int MT, int Q>
__device__ __forceinline__ void ds_a(const unsigned short* At, int rA, int cb,
                                     bf16x8 af[2][2]) {
  constexpr int FPP = MT / 4;
#pragma unroll
  for (int f = 0; f < FPP; ++f) {
    af[f][0] = read_frag(At, rA + (FPP * Q + f) * 16, cb);
    af[f][1] = read_frag(At, rA + (FPP * Q + f) * 16, 64 + cb);
  }
}
// HALF=0: ni 0,1 ; HALF=1: ni 2,3  (4 x ds_read_b128 each)
template <int HALF>
__device__ __forceinline__ void ds_b_half(const unsigned short* Bt, int rB,
                                          int cb, bf16x8 B[4][2]) {
#pragma unroll
  for (int ni = 2 * HALF; ni < 2 * HALF + 2; ++ni) {
    B[ni][0] = read_frag(Bt, rB + ni * 16, cb);
    B[ni][1] = read_frag(Bt, rB + ni * 16, 64 + cb);
  }
}
template <int MT, int Q>
__device__ __forceinline__ void mfma_q(const bf16x8 af[2][2],
                                       const bf16x8 B[4][2],
                                       f32x4 (&acc)[MT][4]) {
  constexpr int FPP = MT / 4;
#pragma unroll
  for (int f = 0; f < FPP; ++f)
#pragma unroll
    for (int ni = 0; ni < 4; ++ni) {
      acc[FPP * Q + f][ni] = mfma16(af[f][0], B[ni][0], acc[FPP * Q + f][ni]);
      acc[FPP * Q + f][ni] = mfma16(af[f][1], B[ni][1], acc[FPP * Q + f][ni]);
    }
}

// Single barrier per phase (at END). Reads complete inside the MFMA cluster
// via compiler-staggered lgkm waits; end barrier orders them before any
// later stage-issue of the same region.
#define PH_TAIL(QN, BRG) do { \
  __builtin_amdgcn_s_setprio(1); \
  mfma_q<MT, QN>(af, BRG, acc); \
  __builtin_amdgcn_s_setprio(0); \
  __builtin_amdgcn_s_barrier(); \
} while (0)

// MT*32-row x 256-col output tile over K = NT*64 (NT even, >=2).
template <int MT>
__device__ __forceinline__ void run_tile(
    const unsigned short* pA, const unsigned short* pB, long long lda,
    long long ldb, int NT, unsigned short* As0, unsigned short* As1,
    unsigned short* Bs0, unsigned short* Bs1, int wid, int rA, int rB, int cb,
    f32x4 (&acc)[MT][4]) {
  bf16x8 BA[4][2], BBr[4][2], af[2][2];
  stage_half(pA, lda, 0, As0, 0, wid);
  if constexpr (MT == 8) stage_half(pA, lda, 0, As0, 1, wid);
  stage_half(pB, ldb, 0, Bs0, 0, wid);
  stage_half(pB, ldb, 0, Bs0, 1, wid);
  stage_half(pB, ldb, 64, Bs1, 0, wid);
  stage_half(pB, ldb, 64, Bs1, 1, wid);
  WAIT_VM(4);  // retire A0,B0; leave B1 (4 loads)
  __builtin_amdgcn_s_barrier();
  ds_b_half<0>(Bs0, rB, cb, BA);  // BA-lo; BA-hi read at P1

  const int NITER = NT / 2 - 1;
  for (int i = 0; i < NITER; ++i) {
    const long long kA1 = (long long)(2 * i + 1) * 64;
    const long long kN2 = (long long)(2 * i + 2) * 64;
    const long long kB3 = (long long)(2 * i + 3) * 64;
    // P1
    ds_b_half<1>(Bs0, rB, cb, BA);
    ds_a<MT, 0>(As0, rA, cb, af); stage_half(pA, lda, kA1, As1, 0, wid);
    PH_TAIL(0, BA);
    // P2
    ds_a<MT, 1>(As0, rA, cb, af);
    if constexpr (MT == 8) stage_half(pA, lda, kA1, As1, 1, wid);
    PH_TAIL(1, BA);
    // P3
    ds_a<MT, 2>(As0, rA, cb, af); stage_half(pB, ldb, kN2, Bs0, 0, wid);
    PH_TAIL(2, BA);
    // P4
    WAIT_VM(2);  // retire prev Bs1 + As1; leave P3
    ds_a<MT, 3>(As0, rA, cb, af); ds_b_half<0>(Bs1, rB, cb, BBr);
    stage_half(pB, ldb, kN2, Bs0, 1, wid);
    PH_TAIL(3, BA);
    // P5
    ds_b_half<1>(Bs1, rB, cb, BBr);
    ds_a<MT, 0>(As1, rA, cb, af); stage_half(pA, lda, kN2, As0, 0, wid);
    PH_TAIL(0, BBr);
    // P6
    ds_a<MT, 1>(As1, rA, cb, af);
    if constexpr (MT == 8) stage_half(pA, lda, kN2, As0, 1, wid);
    PH_TAIL(1, BBr);
    // P7
    ds_a<MT, 2>(As1, rA, cb, af); stage_half(pB, ldb, kB3, Bs1, 0, wid);
    PH_TAIL(2, BBr);
    // P8
    WAIT_VM(2);  // retire Bs0 + As0; leave P7
    ds_a<MT, 3>(As1, rA, cb, af); ds_b_half<0>(Bs0, rB, cb, BA);
    stage_half(pB, ldb, kB3, Bs1, 1, wid);
    PH_TAIL(3, BBr);
  }
  // drain
  const long long kL = (long long)(NT - 1) * 64;
  ds_b_half<1>(Bs0, rB, cb, BA);
  ds_a<MT, 0>(As0, rA, cb, af); stage_half(pA, lda, kL, As1, 0, wid);
  PH_TAIL(0, BA);
  ds_a<MT, 1>(As0, rA, cb, af);
  if constexpr (MT == 8) stage_half(pA, lda, kL, As1, 1, wid);
  PH_TAIL(1, BA);
  ds_a<MT, 2>(As0, rA, cb, af); PH_TAIL(2, BA);
  if constexpr (MT == 8) { WAIT_VM(4); } else { WAIT_VM(2); }
  ds_a<MT, 3>(As0, rA, cb, af); ds_b_half<0>(Bs1, rB, cb, BBr);
  PH_TAIL(3, BA);
  WAIT_VM(0);
  ds_b_half<1>(Bs1, rB, cb, BBr);
  ds_a<MT, 0>(As1, rA, cb, af); PH_TAIL(0, BBr);
  ds_a<MT, 1>(As1, rA, cb, af); PH_TAIL(1, BBr);
  ds_a<MT, 2>(As1, rA, cb, af); PH_TAIL(2, BBr);
  ds_a<MT, 3>(As1, rA, cb, af); PH_TAIL(3, BBr);
}

struct TC {
  int wid, lane, wm, wn, rA, rB, cb, rr, ccl, rowt, colg;
};
template <int MT>
__device__ __forceinline__ TC tc_setup() {
  TC t;
  const int tid = threadIdx.x;
  t.wid = tid >> 6;
  t.lane = tid & 63;
  t.wm = t.wid >> 2;
  t.wn = t.wid & 3;
  const int l16 = t.lane & 15;
  t.rA = t.wm * (MT * 16) + l16;
  t.rB = t.wn * 64 + l16;
  t.cb = (t.lane >> 4) * 16;
  t.rr = (t.lane >> 4) * 4;
  t.ccl = l16;
  t.rowt = tid >> 3;
  t.colg = (((tid & 7) ^ ((tid >> 3) & 7)) * 8);  // inverse of read swizzle
  return t;
}

#define SHARED_TILES8() \
  __shared__ __align__(16) unsigned short As0[16384], As1[16384]; \
  __shared__ __align__(16) unsigned short Bs0[16384], Bs1[16384]
#define SHARED_TILES4() \
  __shared__ __align__(16) unsigned short As0[8192], As1[8192]; \
  __shared__ __align__(16) unsigned short Bs0[16384], Bs1[16384]

// ---- QK fused projection: C[16384][2048] -> Q | K ----
__global__ __launch_bounds__(512, 2) void qk_kernel(
    const unsigned short* __restrict__ X, const unsigned short* __restrict__ W,
    const float* __restrict__ bq, const float* __restrict__ bk,
    unsigned short* __restrict__ Q, unsigned short* __restrict__ K) {
  SHARED_TILES8();
  const int lin = blockIdx.y * 8 + blockIdx.x;
  const int swz = (lin & 7) * 64 + (lin >> 3);
  const int m0 = (swz >> 3) * 256, n0 = (swz & 7) * 256;
  TC t = tc_setup<8>();
  const unsigned short* pA = X + (long long)(m0 + t.rowt) * HD + t.colg;
  const unsigned short* pB = W + (long long)(n0 + t.rowt) * HD + t.colg;
  f32x4 acc[8][4] = {};
  run_tile<8>(pA, pB, HD, HD, 16, As0, As1, Bs0, Bs1, t.wid, t.rA, t.rB, t.cb, acc);
#pragma unroll
  for (int mi = 0; mi < 8; ++mi)
#pragma unroll
    for (int ni = 0; ni < 4; ++ni) {
      const int gn = n0 + t.wn * 64 + ni * 16 + t.ccl;
      const float bias = (gn < 1024) ? bq[gn] : bk[gn - 1024];
      unsigned short* dst = (gn < 1024) ? (Q + gn) : (K + gn - 1024);
#pragma unroll
      for (int j = 0; j < 4; ++j) {
        const int gm = m0 + t.wm * 128 + mi * 16 + t.rr + j;
        dst[(long long)gm * HD] = f2bf(acc[mi][ni][j] + bias);
      }
    }
}

// ---- fused middle, grid 576:
// 0..255 = V^T (MT8); 256..511 = scores full tiles tt 0..31 (MT8);
// 512..575 = scores half tiles of row-block ii=7 (MT4, dispatched last) ----
__global__ __launch_bounds__(512, 2) void mid_kernel(
    const unsigned short* __restrict__ Wv, const unsigned short* __restrict__ X,
    const float* __restrict__ bv, unsigned short* __restrict__ Vt,
    const unsigned short* __restrict__ Q, const unsigned short* __restrict__ Km,
    const int* __restrict__ mask, unsigned short* __restrict__ S,
    float* __restrict__ rowsum) {
  SHARED_TILES8();
  if (blockIdx.x < 256) {
    TC t = tc_setup<8>();
    const int lin = blockIdx.x;
    const int swz = (lin & 7) * 32 + (lin >> 3);
    const int m0 = (swz & 3) * 256, n0 = (swz >> 2) * 256;
    const unsigned short* pA = Wv + (long long)(m0 + t.rowt) * HD + t.colg;
    const unsigned short* pB = X + (long long)(n0 + t.rowt) * HD + t.colg;
    f32x4 acc[8][4] = {};
    run_tile<8>(pA, pB, HD, HD, 16, As0, As1, Bs0, Bs1, t.wid, t.rA, t.rB,
                t.cb, acc);
#pragma unroll
    for (int mi = 0; mi < 8; ++mi)
#pragma unroll
      for (int ni = 0; ni < 4; ++ni) {
        const int gn = n0 + t.wn * 64 + ni * 16 + t.ccl;  // gs
        const long long base = (long long)(gn >> 11) * SH + (gn & 2047);
#pragma unroll
        for (int j = 0; j < 4; ++j) {
          const int gm = m0 + t.wm * 128 + mi * 16 + t.rr + j;  // d
          Vt[base + (long long)gm * SS] = f2bf(acc[mi][ni][j] + bv[gm]);
        }
      }
  } else if (blockIdx.x < 512) {
    // scores full tiles: tt 0..31 (rows ii 0..6 plus ii=7 jj<... tt<32)
    TC t = tc_setup<8>();
    const int s = blockIdx.x - 256;    // 0..255
    const long long b = s & 7;
    int tt = s >> 3;                   // 0..31
    int ii = 0, base = 0;
    while (tt >= base + ii + 1) { base += ii + 1; ++ii; }
    const int jj = tt - base;
    const int m0 = ii * 256, n0 = jj * 256;
    const unsigned short* pA =
        Q + b * SH + (long long)(m0 + t.rowt) * HD + t.colg;
    const unsigned short* pB =
        Km + b * SH + (long long)(n0 + t.rowt) * HD + t.colg;
    f32x4 acc[8][4] = {};
    run_tile<8>(pA, pB, HD, HD, 16, As0, As1, Bs0, Bs1, t.wid, t.rA, t.rB,
                t.cb, acc);
    unsigned short* Sb = S + b * (long long)SS * SS;
    const int* mb = mask + b * SS;
    float* rs = rowsum + b * SS;
    float* rsl = reinterpret_cast<float*>(As0);  // 4KB scratch, LDS dead
#pragma unroll
    for (int mi = 0; mi < 8; ++mi)
#pragma unroll
      for (int j = 0; j < 4; ++j) {
        const int gm = m0 + t.wm * 128 + mi * 16 + t.rr + j;
        float rsum = 0.0f;
#pragma unroll
        for (int ni = 0; ni < 4; ++ni) {
          const int gn = n0 + t.wn * 64 + ni * 16 + t.ccl;
          const bool dead = (gn > gm) || (mb[gn] == 0);
          const float pv = dead ? 0.0f : __expf(acc[mi][ni][j] * 0.03125f);
          Sb[(long long)gm * SS + gn] = f2bf(pv);
          rsum += pv;
        }
#pragma unroll
        for (int o = 1; o < 16; o <<= 1) rsum += __shfl_xor(rsum, o);
        if (t.ccl == 0)
          rsl[t.wn * 256 + (t.wm * 128 + mi * 16 + t.rr + j)] = rsum;
      }
    __syncthreads();
    const int tid = threadIdx.x;
    if (tid < 256) {
      const float v =
          rsl[tid] + rsl[256 + tid] + rsl[512 + tid] + rsl[768 + tid];
      atomicAdd(&rs[m0 + tid], v);
    }
  } else {
    // scores half tiles (MT4): row-block ii=7 (tt 32..35), 128x256 each.
    TC t = tc_setup<4>();
    const int s2 = blockIdx.x - 512;   // 0..63
    const long long b = s2 & 7;
    const int h = s2 >> 3;             // 0..7
    const int jj = 4 + (h >> 1);       // 4..7
    const int m0 = 7 * 256 + (h & 1) * 128;
    const int n0 = jj * 256;
    const unsigned short* pA =
        Q + b * SH + (long long)(m0 + t.rowt) * HD + t.colg;
    const unsigned short* pB =
        Km + b * SH + (long long)(n0 + t.rowt) * HD + t.colg;
    f32x4 acc[4][4] = {};
    run_tile<4>(pA, pB, HD, HD, 16, As0, As1, Bs0, Bs1, t.wid, t.rA, t.rB,
                t.cb, acc);
    unsigned short* Sb = S + b * (long long)SS * SS;
    const int* mb = mask + b * SS;
    float* rs = rowsum + b * SS;
    float* rsl = reinterpret_cast<float*>(As0);  // 2KB scratch
#pragma unroll
    for (int mi = 0; mi < 4; ++mi)
#pragma unroll
      for (int j = 0; j < 4; ++j) {
        const int lrow = t.wm * 64 + mi * 16 + t.rr + j;  // 0..127
        const int gm = m0 + lrow;
        float rsum = 0.0f;
#pragma unroll
        for (int ni = 0; ni < 4; ++ni) {
          const int gn = n0 + t.wn * 64 + ni * 16 + t.ccl;
          const bool dead = (gn > gm) || (mb[gn] == 0);
          const float pv = dead ? 0.0f : __expf(acc[mi][ni][j] * 0.03125f);
          Sb[(long long)gm * SS + gn] = f2bf(pv);
          rsum += pv;
        }
#pragma unroll
        for (int o = 1; o < 16; o <<= 1) rsum += __shfl_xor(rsum, o);
        if (t.ccl == 0) rsl[t.wn * 128 + lrow] = rsum;
      }
    __syncthreads();
    const int tid = threadIdx.x;
    if (tid < 128) {
      const float v =
          rsl[tid] + rsl[128 + tid] + rsl[256 + tid] + rsl[384 + tid];
      atomicAdd(&rs[m0 + tid], v);
    }
  }
}

// ---- PV: paired m-tiles p/(15-p) (128 rows), uniform 34 K-tiles; /rowsum ----
__global__ __launch_bounds__(512, 2) void pv_kernel(
    const unsigned short* __restrict__ S, const unsigned short* __restrict__ Vt,
    const float* __restrict__ rowsum, unsigned short* __restrict__ AO) {
  SHARED_TILES4();
  const int bid = blockIdx.x;
  const long long b = bid & 7;       // batch -> XCD pin
  const int r = bid >> 3;            // 0..31
  const int p = r & 7;
  const int n0 = (r >> 3) * 256;
  const unsigned short* Sb = S + b * (long long)SS * SS;
  const unsigned short* Vb = Vt + b * SH;
  const float* rs = rowsum + b * SS;
  TC t = tc_setup<4>();

  for (int pass = 0; pass < 2; ++pass) {
    const int mi0 = pass ? 15 - p : p;
    const int m0 = mi0 * 128;
    const int NT = 2 * (mi0 + 1);
    const unsigned short* pA = Sb + (long long)(m0 + t.rowt) * SS + t.colg;
    const unsigned short* pB = Vb + (long long)(n0 + t.rowt) * SS + t.colg;
    f32x4 acc[4][4] = {};
    run_tile<4>(pA, pB, SS, SS, NT, As0, As1, Bs0, Bs1, t.wid, t.rA, t.rB,
                t.cb, acc);
#pragma unroll
    for (int mi = 0; mi < 4; ++mi)
#pragma unroll
      for (int j = 0; j < 4; ++j) {
        const int gm = m0 + t.wm * 64 + mi * 16 + t.rr + j;
        const float inv = 1.0f / rs[gm];
#pragma unroll
        for (int ni = 0; ni < 4; ++ni) {
          const int gn = n0 + t.wn * 64 + ni * 16 + t.ccl;
          AO[(b * SS + gm) * (long long)HD + gn] = f2bf(acc[mi][ni][j] * inv);
        }
      }
    __syncthreads();  // LDS reuse safety between passes
  }
}

// ---- output projection: f32 out ----
__global__ __launch_bounds__(512, 2) void oproj_kernel(
    const unsigned short* __restrict__ AO, const unsigned short* __restrict__ W,
    const float* __restrict__ bo, float* __restrict__ out) {
  SHARED_TILES8();
  const int lin = blockIdx.x;
  const int swz = (lin & 7) * 32 + (lin >> 3);
  const int n0 = (swz & 3) * 256, m0 = (swz >> 2) * 256;
  TC t = tc_setup<8>();
  const unsigned short* pA = AO + (long long)(m0 + t.rowt) * HD + t.colg;
  const unsigned short* pB = W + (long long)(n0 + t.rowt) * HD + t.colg;
  f32x4 acc[8][4] = {};
  run_tile<8>(pA, pB, HD, HD, 16, As0, As1, Bs0, Bs1, t.wid, t.rA, t.rB, t.cb, acc);
#pragma unroll
  for (int mi = 0; mi < 8; ++mi)
#pragma unroll
    for (int ni = 0; ni < 4; ++ni) {
      const int gn = n0 + t.wn * 64 + ni * 16 + t.ccl;
      const float bias = bo[gn];
#pragma unroll
      for (int j = 0; j < 4; ++j) {
        const int gm = m0 + t.wm * 128 + mi * 16 + t.rr + j;
        out[(long long)gm * HD + gn] = acc[mi][ni][j] + bias;
      }
    }
}

// ---- single cast dispatch: x + 4 weights -> bf16, rowsum -> 0 ----
__global__ __launch_bounds__(256) void cast_all(
    const float* __restrict__ x, const float* __restrict__ wq,
    const float* __restrict__ wk, const float* __restrict__ wv,
    const float* __restrict__ wo, unsigned short* __restrict__ xb,
    unsigned short* __restrict__ wqkb, unsigned short* __restrict__ wvb,
    unsigned short* __restrict__ wob, float* __restrict__ rowsum) {
  const int NX4 = (int)((long long)BB * SS * HD / 4);  // 4194304
  const int W4 = HD * HD / 4;                          // 262144
  const int RS4 = BB * SS / 4;                         // 4096
  const int TOT = NX4 + 4 * W4 + RS4;
  int idx = blockIdx.x * blockDim.x + threadIdx.x;
  const int stride = gridDim.x * blockDim.x;
  for (int u = idx; u < TOT; u += stride) {
    if (u >= NX4 + 4 * W4) {
      *reinterpret_cast<float4*>(rowsum + (u - NX4 - 4 * W4) * 4) =
          make_float4(0.f, 0.f, 0.f, 0.f);
      continue;
    }
    const float* src;
    unsigned short* dst;
    int off;
    if (u < NX4) {
      src = x; dst = xb; off = u;
    } else {
      const int v = u - NX4;
      const int seg = v >> 18;
      off = v & (W4 - 1);
      if (seg == 0) { src = wq; dst = wqkb; }
      else if (seg == 1) { src = wk; dst = wqkb + HD * HD; }
      else if (seg == 2) { src = wv; dst = wvb; }
      else { src = wo; dst = wob; }
    }
    float4 f = *reinterpret_cast<const float4*>(src + off * 4);
    ushort4 o;
    o.x = f2bf(f.x); o.y = f2bf(f.y); o.z = f2bf(f.z); o.w = f2bf(f.w);
    *reinterpret_cast<ushort4*>(dst + off * 4) = o;
  }
}

extern "C" void kernel_launch(void* const* d_in, const int* in_sizes, int n_in,
                              void* d_out, int out_size, void* d_ws, size_t ws_size,
                              hipStream_t stream) {
  const float* x = (const float*)d_in[0];
  const int* amask = (const int*)d_in[1];
  const float* wq = (const float*)d_in[2];
  const float* bq = (const float*)d_in[3];
  const float* wk = (const float*)d_in[4];
  const float* bk = (const float*)d_in[5];
  const float* wv = (const float*)d_in[6];
  const float* bv = (const float*)d_in[7];
  const float* wo = (const float*)d_in[8];
  const float* bo = (const float*)d_in[9];
  float* out = (float*)d_out;

  const long long NX = (long long)BB * SS * HD;
  char* p = (char*)d_ws;
  unsigned short* xb = (unsigned short*)p;    p += NX * 2;
  unsigned short* wqkb = (unsigned short*)p;  p += 2LL * HD * HD * 2;
  unsigned short* wvb = (unsigned short*)p;   p += (long long)HD * HD * 2;
  unsigned short* wob = (unsigned short*)p;   p += (long long)HD * HD * 2;
  unsigned short* Qb = (unsigned short*)p;    p += NX * 2;
  unsigned short* Kb = (unsigned short*)p;    p += NX * 2;
  unsigned short* Vtb = (unsigned short*)p;   p += NX * 2;  // [b][d][s]
  unsigned short* Sb = (unsigned short*)p;    p += (long long)BB * SS * SS * 2;
  float* rowsum = (float*)p;                  p += (long long)BB * SS * 4;
  unsigned short* AOb = xb;  // alias: x dead after QK + mid projections

  cast_all<<<dim3(2048), 256, 0, stream>>>(x, wq, wk, wv, wo, xb, wqkb, wvb,
                                           wob, rowsum);

  qk_kernel<<<dim3(8, 64), 512, 0, stream>>>(xb, wqkb, bq, bk, Qb, Kb);

  mid_kernel<<<dim3(576), 512, 0, stream>>>(wvb, xb, bv, Vtb, Qb, Kb, amask,
                                            Sb, rowsum);

  pv_kernel<<<dim3(256), 512, 0, stream>>>(Sb, Vtb, rowsum, AOb);

  oproj_kernel<<<dim3(256), 512, 0, stream>>>(AOb, wob, bo, out);
}

// Round 19
// 295.799 us; speedup vs baseline: 1.0991x; 1.0149x over previous
//
#include <hip/hip_runtime.h>
#include <hip/hip_bf16.h>

// SingleHeadCausalSelfAttention B=8 S=2048 H=1024 causal.
// R19 = R18 (best, 300.2us) + round repartition: qk(512) and vt(256) are
// mutually independent (both read only xb) -> fused into one 768-block
// dispatch = exactly 3 full rounds. scores standalone: 256 full 256^2 tiles
// + 64 MT4 half-tiles (tail). Round count 4.5 -> 4.3; no schedule changes.

typedef __bf16 bf16x8 __attribute__((ext_vector_type(8)));
typedef float f32x4 __attribute__((ext_vector_type(4)));

static constexpr int HD = 1024;
static constexpr int BB = 8;
static constexpr int SS = 2048;
static constexpr long long SH = (long long)SS * HD;

__device__ __forceinline__ unsigned short f2bf(float f) {
  unsigned u = __builtin_bit_cast(unsigned, f);
  return (unsigned short)((u + 0x7FFFu + ((u >> 16) & 1u)) >> 16);
}
__device__ __forceinline__ f32x4 mfma16(bf16x8 a, bf16x8 b, f32x4 c) {
  return __builtin_amdgcn_mfma_f32_16x16x32_bf16(a, b, c, 0, 0, 0);
}
__device__ __forceinline__ void gload_lds16(const void* g, void* l) {
  __builtin_amdgcn_global_load_lds(
      (const __attribute__((address_space(1))) void*)g,
      (__attribute__((address_space(3))) void*)l, 16, 0, 0);
}

#define WAIT_VM(n) do { asm volatile("s_waitcnt vmcnt(" #n ")" ::: "memory"); \
} while (0)

// swizzled LDS read: logical (row, colbyte) -> byte ^ ((row&7)<<4)
__device__ __forceinline__ bf16x8 read_frag(const unsigned short* tile, int row,
                                            int colb) {
  int byte = row * 128 + colb;
  byte ^= (row & 7) << 4;
  return *reinterpret_cast<const bf16x8*>(
      reinterpret_cast<const char*>(tile) + byte);
}

// stage one half-tile (128 rows x 64 cols bf16); source cols pre-swizzled.
__device__ __forceinline__ void stage_half(const unsigned short* pM,
                                           long long ld, long long kt,
                                           unsigned short* tile, int h,
                                           int wid) {
  const unsigned short* s = pM + (long long)(h * 128) * ld + kt;
  gload_lds16(s, tile + h * 8192 + wid * 512);
  gload_lds16(s + 64 * ld, tile + h * 8192 + 4096 + wid * 512);
}

template <int MT, int Q>
__device__ __forceinline__ void ds_a(const unsigned short* At, int rA, int cb,
                                     bf16x8 af[2][2]) {
  constexpr int FPP = MT / 4;
#pragma unroll
  for (int f = 0; f < FPP; ++f) {
    af[f][0] = read_frag(At, rA + (FPP * Q + f) * 16, cb);
    af[f][1] = read_frag(At, rA + (FPP * Q + f) * 16, 64 + cb);
  }
}
// HALF=0: ni 0,1 ; HALF=1: ni 2,3  (4 x ds_read_b128 each)
template <int HALF>
__device__ __forceinline__ void ds_b_half(const unsigned short* Bt, int rB,
                                          int cb, bf16x8 B[4][2]) {
#pragma unroll
  for (int ni = 2 * HALF; ni < 2 * HALF + 2; ++ni) {
    B[ni][0] = read_frag(Bt, rB + ni * 16, cb);
    B[ni][1] = read_frag(Bt, rB + ni * 16, 64 + cb);
  }
}
template <int MT, int Q>
__device__ __forceinline__ void mfma_q(const bf16x8 af[2][2],
                                       const bf16x8 B[4][2],
                                       f32x4 (&acc)[MT][4]) {
  constexpr int FPP = MT / 4;
#pragma unroll
  for (int f = 0; f < FPP; ++f)
#pragma unroll
    for (int ni = 0; ni < 4; ++ni) {
      acc[FPP * Q + f][ni] = mfma16(af[f][0], B[ni][0], acc[FPP * Q + f][ni]);
      acc[FPP * Q + f][ni] = mfma16(af[f][1], B[ni][1], acc[FPP * Q + f][ni]);
    }
}

// Single barrier per phase (at END). Reads complete inside the MFMA cluster
// via compiler-staggered lgkm waits; end barrier orders them before any
// later stage-issue of the same region.
#define PH_TAIL(QN, BRG) do { \
  __builtin_amdgcn_s_setprio(1); \
  mfma_q<MT, QN>(af, BRG, acc); \
  __builtin_amdgcn_s_setprio(0); \
  __builtin_amdgcn_s_barrier(); \
} while (0)

// MT*32-row x 256-col output tile over K = NT*64 (NT even, >=2).
template <int MT>
__device__ __forceinline__ void run_tile(
    const unsigned short* pA, const unsigned short* pB, long long lda,
    long long ldb, int NT, unsigned short* As0, unsigned short* As1,
    unsigned short* Bs0, unsigned short* Bs1, int wid, int rA, int rB, int cb,
    f32x4 (&acc)[MT][4]) {
  bf16x8 BA[4][2], BBr[4][2], af[2][2];
  stage_half(pA, lda, 0, As0, 0, wid);
  if constexpr (MT == 8) stage_half(pA, lda, 0, As0, 1, wid);
  stage_half(pB, ldb, 0, Bs0, 0, wid);
  stage_half(pB, ldb, 0, Bs0, 1, wid);
  stage_half(pB, ldb, 64, Bs1, 0, wid);
  stage_half(pB, ldb, 64, Bs1, 1, wid);
  WAIT_VM(4);  // retire A0,B0; leave B1 (4 loads)
  __builtin_amdgcn_s_barrier();
  ds_b_half<0>(Bs0, rB, cb, BA);  // BA-lo; BA-hi read at P1

  const int NITER = NT / 2 - 1;
  for (int i = 0; i < NITER; ++i) {
    const long long kA1 = (long long)(2 * i + 1) * 64;
    const long long kN2 = (long long)(2 * i + 2) * 64;
    const long long kB3 = (long long)(2 * i + 3) * 64;
    // P1
    ds_b_half<1>(Bs0, rB, cb, BA);
    ds_a<MT, 0>(As0, rA, cb, af); stage_half(pA, lda, kA1, As1, 0, wid);
    PH_TAIL(0, BA);
    // P2
    ds_a<MT, 1>(As0, rA, cb, af);
    if constexpr (MT == 8) stage_half(pA, lda, kA1, As1, 1, wid);
    PH_TAIL(1, BA);
    // P3
    ds_a<MT, 2>(As0, rA, cb, af); stage_half(pB, ldb, kN2, Bs0, 0, wid);
    PH_TAIL(2, BA);
    // P4
    WAIT_VM(2);  // retire prev Bs1 + As1; leave P3
    ds_a<MT, 3>(As0, rA, cb, af); ds_b_half<0>(Bs1, rB, cb, BBr);
    stage_half(pB, ldb, kN2, Bs0, 1, wid);
    PH_TAIL(3, BA);
    // P5
    ds_b_half<1>(Bs1, rB, cb, BBr);
    ds_a<MT, 0>(As1, rA, cb, af); stage_half(pA, lda, kN2, As0, 0, wid);
    PH_TAIL(0, BBr);
    // P6
    ds_a<MT, 1>(As1, rA, cb, af);
    if constexpr (MT == 8) stage_half(pA, lda, kN2, As0, 1, wid);
    PH_TAIL(1, BBr);
    // P7
    ds_a<MT, 2>(As1, rA, cb, af); stage_half(pB, ldb, kB3, Bs1, 0, wid);
    PH_TAIL(2, BBr);
    // P8
    WAIT_VM(2);  // retire Bs0 + As0; leave P7
    ds_a<MT, 3>(As1, rA, cb, af); ds_b_half<0>(Bs0, rB, cb, BA);
    stage_half(pB, ldb, kB3, Bs1, 1, wid);
    PH_TAIL(3, BBr);
  }
  // drain
  const long long kL = (long long)(NT - 1) * 64;
  ds_b_half<1>(Bs0, rB, cb, BA);
  ds_a<MT, 0>(As0, rA, cb, af); stage_half(pA, lda, kL, As1, 0, wid);
  PH_TAIL(0, BA);
  ds_a<MT, 1>(As0, rA, cb, af);
  if constexpr (MT == 8) stage_half(pA, lda, kL, As1, 1, wid);
  PH_TAIL(1, BA);
  ds_a<MT, 2>(As0, rA, cb, af); PH_TAIL(2, BA);
  if constexpr (MT == 8) { WAIT_VM(4); } else { WAIT_VM(2); }
  ds_a<MT, 3>(As0, rA, cb, af); ds_b_half<0>(Bs1, rB, cb, BBr);
  PH_TAIL(3, BA);
  WAIT_VM(0);
  ds_b_half<1>(Bs1, rB, cb, BBr);
  ds_a<MT, 0>(As1, rA, cb, af); PH_TAIL(0, BBr);
  ds_a<MT, 1>(As1, rA, cb, af); PH_TAIL(1, BBr);
  ds_a<MT, 2>(As1, rA, cb, af); PH_TAIL(2, BBr);
  ds_a<MT, 3>(As1, rA, cb, af); PH_TAIL(3, BBr);
}

struct TC {
  int wid, lane, wm, wn, rA, rB, cb, rr, ccl, rowt, colg;
};
template <int MT>
__device__ __forceinline__ TC tc_setup() {
  TC t;
  const int tid = threadIdx.x;
  t.wid = tid >> 6;
  t.lane = tid & 63;
  t.wm = t.wid >> 2;
  t.wn = t.wid & 3;
  const int l16 = t.lane & 15;
  t.rA = t.wm * (MT * 16) + l16;
  t.rB = t.wn * 64 + l16;
  t.cb = (t.lane >> 4) * 16;
  t.rr = (t.lane >> 4) * 4;
  t.ccl = l16;
  t.rowt = tid >> 3;
  t.colg = (((tid & 7) ^ ((tid >> 3) & 7)) * 8);  // inverse of read swizzle
  return t;
}

#define SHARED_TILES8() \
  __shared__ __align__(16) unsigned short As0[16384], As1[16384]; \
  __shared__ __align__(16) unsigned short Bs0[16384], Bs1[16384]
#define SHARED_TILES4() \
  __shared__ __align__(16) unsigned short As0[8192], As1[8192]; \
  __shared__ __align__(16) unsigned short Bs0[16384], Bs1[16384]

// ---- fused QK + V^T, grid 768 = exactly 3 rounds:
// 0..511 = QK projection tiles; 512..767 = V^T (A=Wv, B=x) tiles ----
__global__ __launch_bounds__(512, 2) void qkvt_kernel(
    const unsigned short* __restrict__ X, const unsigned short* __restrict__ W,
    const unsigned short* __restrict__ Wv, const float* __restrict__ bq,
    const float* __restrict__ bk, const float* __restrict__ bv,
    unsigned short* __restrict__ Q, unsigned short* __restrict__ K,
    unsigned short* __restrict__ Vt) {
  SHARED_TILES8();
  TC t = tc_setup<8>();
  if (blockIdx.x < 512) {
    const int lin = blockIdx.x;
    const int swz = (lin & 7) * 64 + (lin >> 3);
    const int m0 = (swz >> 3) * 256, n0 = (swz & 7) * 256;
    const unsigned short* pA = X + (long long)(m0 + t.rowt) * HD + t.colg;
    const unsigned short* pB = W + (long long)(n0 + t.rowt) * HD + t.colg;
    f32x4 acc[8][4] = {};
    run_tile<8>(pA, pB, HD, HD, 16, As0, As1, Bs0, Bs1, t.wid, t.rA, t.rB,
                t.cb, acc);
#pragma unroll
    for (int mi = 0; mi < 8; ++mi)
#pragma unroll
      for (int ni = 0; ni < 4; ++ni) {
        const int gn = n0 + t.wn * 64 + ni * 16 + t.ccl;
        const float bias = (gn < 1024) ? bq[gn] : bk[gn - 1024];
        unsigned short* dst = (gn < 1024) ? (Q + gn) : (K + gn - 1024);
#pragma unroll
        for (int j = 0; j < 4; ++j) {
          const int gm = m0 + t.wm * 128 + mi * 16 + t.rr + j;
          dst[(long long)gm * HD] = f2bf(acc[mi][ni][j] + bias);
        }
      }
  } else {
    const int lin = blockIdx.x - 512;  // 0..255
    const int swz = (lin & 7) * 32 + (lin >> 3);
    const int m0 = (swz & 3) * 256, n0 = (swz >> 2) * 256;
    const unsigned short* pA = Wv + (long long)(m0 + t.rowt) * HD + t.colg;
    const unsigned short* pB = X + (long long)(n0 + t.rowt) * HD + t.colg;
    f32x4 acc[8][4] = {};
    run_tile<8>(pA, pB, HD, HD, 16, As0, As1, Bs0, Bs1, t.wid, t.rA, t.rB,
                t.cb, acc);
#pragma unroll
    for (int mi = 0; mi < 8; ++mi)
#pragma unroll
      for (int ni = 0; ni < 4; ++ni) {
        const int gn = n0 + t.wn * 64 + ni * 16 + t.ccl;  // gs
        const long long base = (long long)(gn >> 11) * SH + (gn & 2047);
#pragma unroll
        for (int j = 0; j < 4; ++j) {
          const int gm = m0 + t.wm * 128 + mi * 16 + t.rr + j;  // d
          Vt[base + (long long)gm * SS] = f2bf(acc[mi][ni][j] + bv[gm]);
        }
      }
  }
}

// ---- scores, grid 320: 0..255 full 256^2 tiles (tt 0..31, MT8);
// 256..319 half tiles of row-block ii=7 (MT4, dispatched last) ----
__global__ __launch_bounds__(512, 2) void scores_kernel(
    const unsigned short* __restrict__ Q, const unsigned short* __restrict__ Km,
    const int* __restrict__ mask, unsigned short* __restrict__ S,
    float* __restrict__ rowsum) {
  SHARED_TILES8();
  if (blockIdx.x < 256) {
    TC t = tc_setup<8>();
    const int s = blockIdx.x;          // 0..255
    const long long b = s & 7;
    int tt = s >> 3;                   // 0..31
    int ii = 0, base = 0;
    while (tt >= base + ii + 1) { base += ii + 1; ++ii; }
    const int jj = tt - base;
    const int m0 = ii * 256, n0 = jj * 256;
    const unsigned short* pA =
        Q + b * SH + (long long)(m0 + t.rowt) * HD + t.colg;
    const unsigned short* pB =
        Km + b * SH + (long long)(n0 + t.rowt) * HD + t.colg;
    f32x4 acc[8][4] = {};
    run_tile<8>(pA, pB, HD, HD, 16, As0, As1, Bs0, Bs1, t.wid, t.rA, t.rB,
                t.cb, acc);
    unsigned short* Sb = S + b * (long long)SS * SS;
    const int* mb = mask + b * SS;
    float* rs = rowsum + b * SS;
    float* rsl = reinterpret_cast<float*>(As0);  // 4KB scratch, LDS dead
#pragma unroll
    for (int mi = 0; mi < 8; ++mi)
#pragma unroll
      for (int j = 0; j < 4; ++j) {
        const int gm = m0 + t.wm * 128 + mi * 16 + t.rr + j;
        float rsum = 0.0f;
#pragma unroll
        for (int ni = 0; ni < 4; ++ni) {
          const int gn = n0 + t.wn * 64 + ni * 16 + t.ccl;
          const bool dead = (gn > gm) || (mb[gn] == 0);
          const float pv = dead ? 0.0f : __expf(acc[mi][ni][j] * 0.03125f);
          Sb[(long long)gm * SS + gn] = f2bf(pv);
          rsum += pv;
        }
#pragma unroll
        for (int o = 1; o < 16; o <<= 1) rsum += __shfl_xor(rsum, o);
        if (t.ccl == 0)
          rsl[t.wn * 256 + (t.wm * 128 + mi * 16 + t.rr + j)] = rsum;
      }
    __syncthreads();
    const int tid = threadIdx.x;
    if (tid < 256) {
      const float v =
          rsl[tid] + rsl[256 + tid] + rsl[512 + tid] + rsl[768 + tid];
      atomicAdd(&rs[m0 + tid], v);
    }
  } else {
    // half tiles (MT4): row-block ii=7 (tt 32..35), 128x256 each.
    TC t = tc_setup<4>();
    const int s2 = blockIdx.x - 256;   // 0..63
    const long long b = s2 & 7;
    const int h = s2 >> 3;             // 0..7
    const int jj = 4 + (h >> 1);       // 4..7
    const int m0 = 7 * 256 + (h & 1) * 128;
    const int n0 = jj * 256;
    const unsigned short* pA =
        Q + b * SH + (long long)(m0 + t.rowt) * HD + t.colg;
    const unsigned short* pB =
        Km + b * SH + (long long)(n0 + t.rowt) * HD + t.colg;
    f32x4 acc[4][4] = {};
    run_tile<4>(pA, pB, HD, HD, 16, As0, As1, Bs0, Bs1, t.wid, t.rA, t.rB,
                t.cb, acc);
    unsigned short* Sb = S + b * (long long)SS * SS;
    const int* mb = mask + b * SS;
    float* rs = rowsum + b * SS;
    float* rsl = reinterpret_cast<float*>(As0);  // 2KB scratch
#pragma unroll
    for (int mi = 0; mi < 4; ++mi)
#pragma unroll
      for (int j = 0; j < 4; ++j) {
        const int lrow = t.wm * 64 + mi * 16 + t.rr + j;  // 0..127
        const int gm = m0 + lrow;
        float rsum = 0.0f;
#pragma unroll
        for (int ni = 0; ni < 4; ++ni) {
          const int gn = n0 + t.wn * 64 + ni * 16 + t.ccl;
          const bool dead = (gn > gm) || (mb[gn] == 0);
          const float pv = dead ? 0.0f : __expf(acc[mi][ni][j] * 0.03125f);
          Sb[(long long)gm * SS + gn] = f2bf(pv);
          rsum += pv;
        }
#pragma unroll
        for (int o = 1; o < 16; o <<= 1) rsum += __shfl_xor(rsum, o);
        if (t.ccl == 0) rsl[t.wn * 128 + lrow] = rsum;
      }
    __syncthreads();
    const int tid = threadIdx.x;
    if (tid < 128) {
      const float v =
          rsl[tid] + rsl[128 + tid] + rsl[256 + tid] + rsl[384 + tid];
      atomicAdd(&rs[m0 + tid], v);
    }
  }
}

// ---- PV: paired m-tiles p/(15-p) (128 rows), uniform 34 K-tiles; /rowsum ----
__global__ __launch_bounds__(512, 2) void pv_kernel(
    const unsigned short* __restrict__ S, const unsigned short* __restrict__ Vt,
    const float* __restrict__ rowsum, unsigned short* __restrict__ AO) {
  SHARED_TILES4();
  const int bid = blockIdx.x;
  const long long b = bid & 7;       // batch -> XCD pin
  const int r = bid >> 3;            // 0..31
  const int p = r & 7;
  const int n0 = (r >> 3) * 256;
  const unsigned short* Sb = S + b * (long long)SS * SS;
  const unsigned short* Vb = Vt + b * SH;
  const float* rs = rowsum + b * SS;
  TC t = tc_setup<4>();

  for (int pass = 0; pass < 2; ++pass) {
    const int mi0 = pass ? 15 - p : p;
    const int m0 = mi0 * 128;
    const int NT = 2 * (mi0 + 1);
    const unsigned short* pA = Sb + (long long)(m0 + t.rowt) * SS + t.colg;
    const unsigned short* pB = Vb + (long long)(n0 + t.rowt) * SS + t.colg;
    f32x4 acc[4][4] = {};
    run_tile<4>(pA, pB, SS, SS, NT, As0, As1, Bs0, Bs1, t.wid, t.rA, t.rB,
                t.cb, acc);
#pragma unroll
    for (int mi = 0; mi < 4; ++mi)
#pragma unroll
      for (int j = 0; j < 4; ++j) {
        const int gm = m0 + t.wm * 64 + mi * 16 + t.rr + j;
        const float inv = 1.0f / rs[gm];
#pragma unroll
        for (int ni = 0; ni < 4; ++ni) {
          const int gn = n0 + t.wn * 64 + ni * 16 + t.ccl;
          AO[(b * SS + gm) * (long long)HD + gn] = f2bf(acc[mi][ni][j] * inv);
        }
      }
    __syncthreads();  // LDS reuse safety between passes
  }
}

// ---- output projection: f32 out ----
__global__ __launch_bounds__(512, 2) void oproj_kernel(
    const unsigned short* __restrict__ AO, const unsigned short* __restrict__ W,
    const float* __restrict__ bo, float* __restrict__ out) {
  SHARED_TILES8();
  const int lin = blockIdx.x;
  const int swz = (lin & 7) * 32 + (lin >> 3);
  const int n0 = (swz & 3) * 256, m0 = (swz >> 2) * 256;
  TC t = tc_setup<8>();
  const unsigned short* pA = AO + (long long)(m0 + t.rowt) * HD + t.colg;
  const unsigned short* pB = W + (long long)(n0 + t.rowt) * HD + t.colg;
  f32x4 acc[8][4] = {};
  run_tile<8>(pA, pB, HD, HD, 16, As0, As1, Bs0, Bs1, t.wid, t.rA, t.rB, t.cb, acc);
#pragma unroll
  for (int mi = 0; mi < 8; ++mi)
#pragma unroll
    for (int ni = 0; ni < 4; ++ni) {
      const int gn = n0 + t.wn * 64 + ni * 16 + t.ccl;
      const float bias = bo[gn];
#pragma unroll
      for (int j = 0; j < 4; ++j) {
        const int gm = m0 + t.wm * 128 + mi * 16 + t.rr + j;
        out[(long long)gm * HD + gn] = acc[mi][ni][j] + bias;
      }
    }
}

// ---- single cast dispatch: x + 4 weights -> bf16, rowsum -> 0 ----
__global__ __launch_bounds__(256) void cast_all(
    const float* __restrict__ x, const float* __restrict__ wq,
    const float* __restrict__ wk, const float* __restrict__ wv,
    const float* __restrict__ wo, unsigned short* __restrict__ xb,
    unsigned short* __restrict__ wqkb, unsigned short* __restrict__ wvb,
    unsigned short* __restrict__ wob, float* __restrict__ rowsum) {
  const int NX4 = (int)((long long)BB * SS * HD / 4);  // 4194304
  const int W4 = HD * HD / 4;                          // 262144
  const int RS4 = BB * SS / 4;                         // 4096
  const int TOT = NX4 + 4 * W4 + RS4;
  int idx = blockIdx.x * blockDim.x + threadIdx.x;
  const int stride = gridDim.x * blockDim.x;
  for (int u = idx; u < TOT; u += stride) {
    if (u >= NX4 + 4 * W4) {
      *reinterpret_cast<float4*>(rowsum + (u - NX4 - 4 * W4) * 4) =
          make_float4(0.f, 0.f, 0.f, 0.f);
      continue;
    }
    const float* src;
    unsigned short* dst;
    int off;
    if (u < NX4) {
      src = x; dst = xb; off = u;
    } else {
      const int v = u - NX4;
      const int seg = v >> 18;
      off = v & (W4 - 1);
      if (seg == 0) { src = wq; dst = wqkb; }
      else if (seg == 1) { src = wk; dst = wqkb + HD * HD; }
      else if (seg == 2) { src = wv; dst = wvb; }
      else { src = wo; dst = wob; }
    }
    float4 f = *reinterpret_cast<const float4*>(src + off * 4);
    ushort4 o;
    o.x = f2bf(f.x); o.y = f2bf(f.y); o.z = f2bf(f.z); o.w = f2bf(f.w);
    *reinterpret_cast<ushort4*>(dst + off * 4) = o;
  }
}

extern "C" void kernel_launch(void* const* d_in, const int* in_sizes, int n_in,
                              void* d_out, int out_size, void* d_ws, size_t ws_size,
                              hipStream_t stream) {
  const float* x = (const float*)d_in[0];
  const int* amask = (const int*)d_in[1];
  const float* wq = (const float*)d_in[2];
  const float* bq = (const float*)d_in[3];
  const float* wk = (const float*)d_in[4];
  const float* bk = (const float*)d_in[5];
  const float* wv = (const float*)d_in[6];
  const float* bv = (const float*)d_in[7];
  const float* wo = (const float*)d_in[8];
  const float* bo = (const float*)d_in[9];
  float* out = (float*)d_out;

  const long long NX = (long long)BB * SS * HD;
  char* p = (char*)d_ws;
  unsigned short* xb = (unsigned short*)p;    p += NX * 2;
  unsigned short* wqkb = (unsigned short*)p;  p += 2LL * HD * HD * 2;
  unsigned short* wvb = (unsigned short*)p;   p += (long long)HD * HD * 2;
  unsigned short* wob = (unsigned short*)p;   p += (long long)HD * HD * 2;
  unsigned short* Qb = (unsigned short*)p;    p += NX * 2;
  unsigned short* Kb = (unsigned short*)p;    p += NX * 2;
  unsigned short* Vtb = (unsigned short*)p;   p += NX * 2;  // [b][d][s]
  unsigned short* Sb = (unsigned short*)p;    p += (long long)BB * SS * SS * 2;
  float* rowsum = (float*)p;                  p += (long long)BB * SS * 4;
  unsigned short* AOb = xb;  // alias: x dead after qkvt

  cast_all<<<dim3(2048), 256, 0, stream>>>(x, wq, wk, wv, wo, xb, wqkb, wvb,
                                           wob, rowsum);

  qkvt_kernel<<<dim3(768), 512, 0, stream>>>(xb, wqkb, wvb, bq, bk, bv, Qb,
                                             Kb, Vtb);

  scores_kernel<<<dim3(320), 512, 0, stream>>>(Qb, Kb, amask, Sb, rowsum);

  pv_kernel<<<dim3(256), 512, 0, stream>>>(Sb, Vtb, rowsum, AOb);

  oproj_kernel<<<dim3(256), 512, 0, stream>>>(AOb, wob, bo, out);
}